// Round 4
// baseline (12067.529 us; speedup 1.0000x reference)
//
#include <hip/hip_runtime.h>
#include <hip/hip_fp16.h>
#include <math.h>

#define NP 65536
#define MP 512
#define SKI 20
#define NBALL 10

#define FNB 32      // fps blocks
#define SKB 256     // sinkhorn blocks

// f32(-1/0.05f) rounds exactly to -20.0f
#define NINV_TAU (-20.0f)
// 1/f32(sqrt(128)) ; sc = 1/sqrt(C)
#define SCF (1.0f / 11.313708305358886719f)
#define SCNT (SCF * NINV_TAU)

typedef unsigned short us8 __attribute__((ext_vector_type(8)));

// ---------------- helpers ----------------

__device__ __forceinline__ float h2f(unsigned short u) {
  return __half2float(__builtin_bit_cast(__half, u));
}

__device__ __forceinline__ void lse_add(float& mm, float& ss, float v) {
  if (v <= mm) { ss += __expf(v - mm); }
  else { ss = fmaf(ss, __expf(mm - v), 1.0f); mm = v; }
}
__device__ __forceinline__ void lse_merge(float& mm, float& ss, float om, float os) {
  float nm = fmaxf(mm, om);
  ss = ss * __expf(mm - nm) + os * __expf(om - nm);
  mm = nm;
}

// global barrier: single monotonic counter, one FAA + one poller per block.
__device__ __forceinline__ void gbar(int* cnt, int ep, int t) {
  __syncthreads();
  if (t == 0) {
    __threadfence();
    __hip_atomic_fetch_add(cnt, 1, __ATOMIC_RELEASE, __HIP_MEMORY_SCOPE_AGENT);
    while (__hip_atomic_load(cnt, __ATOMIC_ACQUIRE, __HIP_MEMORY_SCOPE_AGENT) <
           ep * SKB) {
      __builtin_amdgcn_s_sleep(1);
    }
  }
  __syncthreads();
  __threadfence();
}

// closed-form symmetric 3x3 eigenvalues (ascending), double precision
__device__ void eig3(double a00, double a01, double a02, double a11, double a12,
                     double a22, double* e) {
  double p1 = a01*a01 + a02*a02 + a12*a12;
  double q  = (a00 + a11 + a22) / 3.0;
  double b00 = a00 - q, b11 = a11 - q, b22 = a22 - q;
  double p2 = b00*b00 + b11*b11 + b22*b22 + 2.0*p1;
  if (p2 <= 1e-300) { e[0] = e[1] = e[2] = q; return; }
  double p = sqrt(p2 / 6.0);
  double ip = 1.0 / p;
  double c00 = b00*ip, c01 = a01*ip, c02 = a02*ip;
  double c11 = b11*ip, c12 = a12*ip, c22 = b22*ip;
  double detB = c00*(c11*c22 - c12*c12) - c01*(c01*c22 - c12*c02)
              + c02*(c01*c12 - c11*c02);
  double r = detB / 2.0;
  r = fmin(1.0, fmax(-1.0, r));
  double phi = acos(r) / 3.0;
  double e2 = q + 2.0*p*cos(phi);
  double e0 = q + 2.0*p*cos(phi + 2.0943951023931953);
  double e1 = 3.0*q - e2 - e0;
  e[0] = e0; e[1] = e1; e[2] = e2;
}

// ---------------- kernels ----------------

__global__ void k_init(unsigned long long* __restrict__ slots, int* __restrict__ bar1,
                       int* __restrict__ bar2) {
  int t = threadIdx.x;
  if (t < 3 * FNB) slots[t] = 0ULL;
  if (t < 64) { bar1[t] = 0; bar2[t] = 0; }
}

// pack xyz + |x|^2 into float4
__global__ void k_prep(const float* __restrict__ xyz, float4* __restrict__ xyzs4) {
  int i = blockIdx.x * blockDim.x + threadIdx.x;
  if (i < NP) {
    float x = xyz[3*i+0], y = xyz[3*i+1], z = xyz[3*i+2];
    xyzs4[i] = make_float4(x, y, z, x*x + y*y + z*z);
  }
}

// FPS: 32 blocks x 256 threads, 8 pts/thread in regs. Payload-carrying slot
// barrier, mod-3 phase buffering.
__global__ __launch_bounds__(256) void k_fps3(const float4* __restrict__ xyzs4,
                                              int* __restrict__ cent,
                                              unsigned long long* __restrict__ slots) {
  const int t = threadIdx.x, b = blockIdx.x;
  const int base = (b * 256 + t) * 8;
  float X[8], Y[8], Z[8], D[8];
#pragma unroll
  for (int k = 0; k < 8; ++k) {
    float4 p = xyzs4[base + k];
    X[k] = p.x; Y[k] = p.y; Z[k] = p.z; D[k] = 1e10f;
  }
  __shared__ unsigned long long swave[4];
  __shared__ unsigned long long swin;
  int cur = 0;
  float cx = xyzs4[0].x, cy = xyzs4[0].y, cz = xyzs4[0].z;
  const int lane = t & 63, wid = t >> 6;
  for (int it = 0; it < MP; ++it) {
    if (b == 0 && t == 0) cent[it] = cur;
    float bm = -1.0f; int bi = 0x7fffffff;
#pragma unroll
    for (int k = 0; k < 8; ++k) {
      float dx = X[k] - cx, dy = Y[k] - cy, dz = Z[k] - cz;
      float d = dx*dx + dy*dy + dz*dz;
      float nd = fminf(D[k], d);
      D[k] = nd;
      bool gt = (nd > bm);
      bi = gt ? (base + k) : bi;
      bm = gt ? nd : bm;
    }
    unsigned long long key =
        ((unsigned long long)__float_as_uint(bm) << 32) |
        (unsigned int)(0x7fffffff - bi);
#pragma unroll
    for (int off = 32; off > 0; off >>= 1) {
      unsigned long long o = __shfl_down(key, off);
      key = (o > key) ? o : key;
    }
    if (lane == 0) swave[wid] = key;
    __syncthreads();
    const int p = it % 3, pn = (it + 1) % 3;
    if (t == 0) {
      unsigned long long k0 = swave[0];
      for (int w = 1; w < 4; ++w) k0 = (swave[w] > k0) ? swave[w] : k0;
      __hip_atomic_store(&slots[pn * FNB + b], 0ULL, __ATOMIC_RELAXED,
                         __HIP_MEMORY_SCOPE_AGENT);
      __hip_atomic_store(&slots[p * FNB + b], k0, __ATOMIC_RELEASE,
                         __HIP_MEMORY_SCOPE_AGENT);
    }
    if (wid == 0) {
      unsigned long long v = 0ULL;
      if (lane < FNB) {
        do {
          v = __hip_atomic_load(&slots[p * FNB + lane], __ATOMIC_ACQUIRE,
                                __HIP_MEMORY_SCOPE_AGENT);
        } while (v == 0ULL);
      }
#pragma unroll
      for (int off = 32; off > 0; off >>= 1) {
        unsigned long long o = __shfl_down(v, off);
        v = (o > v) ? o : v;
      }
      if (lane == 0) swin = v;
    }
    __syncthreads();
    unsigned long long wkey = swin;
    cur = 0x7fffffff - (int)(wkey & 0xffffffffu);
    float4 cc = xyzs4[cur];
    cx = cc.x; cy = cc.y; cz = cc.z;
    __syncthreads();
  }
}

// gather proto xyz (+norm) and mean node
__global__ void k_gather1(const float* __restrict__ xyz, const int* __restrict__ cent,
                          float4* __restrict__ pxyzs4, float* __restrict__ meann) {
  __shared__ float sx[512], sy[512], sz[512];
  int m = threadIdx.x;
  int c = cent[m];
  float x = xyz[3*c+0], y = xyz[3*c+1], z = xyz[3*c+2];
  pxyzs4[m] = make_float4(x, y, z, x*x + y*y + z*z);
  sx[m] = x; sy[m] = y; sz[m] = z;
  __syncthreads();
  for (int off = 256; off > 0; off >>= 1) {
    if (m < off) { sx[m] += sx[m+off]; sy[m] += sy[m+off]; sz[m] += sz[m+off]; }
    __syncthreads();
  }
  if (m == 0) {
    meann[0] = sx[0] * (1.0f/512.0f);
    meann[1] = sy[0] * (1.0f/512.0f);
    meann[2] = sz[0] * (1.0f/512.0f);
  }
}

// gather proto features
__global__ void k_gatherf(const float* __restrict__ feats, const int* __restrict__ cent,
                          float* __restrict__ pf) {
  int m = blockIdx.x, c = threadIdx.x;
  pf[m*128 + c] = feats[(size_t)cent[m]*128 + c];
}

// ball query (first 10 smallest indices within radius) + PCA curvature -> dist_ge
__global__ void k_ballpca(const float4* __restrict__ xyzs4,
                          const float4* __restrict__ pxyzs4,
                          const float* __restrict__ meann,
                          float* __restrict__ ge) {
  const int m = blockIdx.x, t = threadIdx.x;
  __shared__ int lidx[256][NBALL];
  __shared__ int s_sel[NBALL];
  __shared__ int s_win;
  __shared__ int s_w4[4];
  float4 q = pxyzs4[m];
  int cnt = 0;
  for (int k = 0; k < 256; ++k) {
    int i = (k << 8) + t;
    float4 p = xyzs4[i];
    float dot = q.x*p.x + q.y*p.y + q.z*p.z;
    float d2 = (q.w + p.w) - 2.0f*dot;
    float d = sqrtf(fmaxf(d2, 0.0f));
    if (!(d > 0.04f) && cnt < NBALL) { lidx[t][cnt] = i; cnt++; }
  }
  __syncthreads();
  int hp = 0;
  for (int r = 0; r < NBALL; ++r) {
    int v = (hp < cnt) ? lidx[t][hp] : 0x7fffffff;
#pragma unroll
    for (int off = 32; off > 0; off >>= 1) v = min(v, __shfl_down(v, off));
    if ((t & 63) == 0) s_w4[t >> 6] = v;
    __syncthreads();
    if (t == 0) s_win = min(min(s_w4[0], s_w4[1]), min(s_w4[2], s_w4[3]));
    __syncthreads();
    int w = s_win;
    if (w != 0x7fffffff && hp < cnt && lidx[t][hp] == w) hp++;
    if (t == 0) s_sel[r] = w;
    __syncthreads();
  }
  if (t == 0) {
    float mx = meann[0], my = meann[1], mz = meann[2];
    int first = (s_sel[0] != 0x7fffffff) ? s_sel[0] : NP;
    float c00=0,c01=0,c02=0,c11=0,c12=0,c22=0;
    for (int r = 0; r < NBALL; ++r) {
      int id = s_sel[r];
      if (id == 0x7fffffff) id = first;
      float nx, ny, nz;
      if (id >= NP) { nx = mx; ny = my; nz = mz; }
      else { float4 p = xyzs4[id]; nx = p.x; ny = p.y; nz = p.z; }
      float dx = nx - q.x, dy = ny - q.y, dz = nz - q.z;
      c00 += dx*dx; c01 += dx*dy; c02 += dx*dz;
      c11 += dy*dy; c12 += dy*dz; c22 += dz*dz;
    }
    double e[3];
    eig3((double)(c00/10.0f + 1e-8f), (double)(c01/10.0f + 1e-8f),
         (double)(c02/10.0f + 1e-8f), (double)(c11/10.0f + 1e-8f),
         (double)(c12/10.0f + 1e-8f), (double)(c22/10.0f + 1e-8f), e);
    float l0 = (float)e[0], l1 = (float)e[1], l2r = (float)e[2];
    float l2 = fmaxf(l2r, 1e-8f);
    float f0 = (l2 - l1) / l2, f1 = (l1 - l0) / l2, f2 = l0 / l2;
    ge[m] = sqrtf(f0*f0 + f1*f1 + f2*f2) / sqrtf(3.0f);
  }
}

// fused sinkhorn 1: 20 x (row pass; gbar; col pass; gbar). Cost recomputed
// from geometry. 256 blocks x 512 threads, persistent.
__global__ __launch_bounds__(512) void k_sk1(const float4* __restrict__ xyzs4,
                                             const float4* __restrict__ pxyzs4,
                                             const float* __restrict__ ge,
                                             float* __restrict__ r,
                                             float* __restrict__ c,
                                             int* __restrict__ cnt) {
  const int t = threadIdx.x, b = blockIdx.x;
  __shared__ float4 sp[MP];
  __shared__ float  su[MP];
  __shared__ float2 red8[8];
  int ep = 0;
  const int row = (b * 512 + t) >> 1, h = t & 1;
  const int lane = t & 63, wid = t >> 6;
  const int jc = 2 * b + (t >> 8), tt = t & 255;
  // loop-invariant state
  sp[t] = pxyzs4[t];
  const float4 q = xyzs4[row];            // row pass: own point
  const int j0 = h << 8;
  const float4 pj = pxyzs4[jc];           // col pass: own proto
  const float g20 = ge[jc] * NINV_TAU;
  __syncthreads();
  for (int it = 0; it < SKI; ++it) {
    su[t] = fmaf(ge[t], NINV_TAU, it ? c[t] : 0.0f);
    __syncthreads();
    // ---- row pass: r_i = -LSE_j(K_ij + c_j) incl pad col ----
    float mm, ss;
    if (h == 0) { mm = 0.0f; ss = 1.0f; } else { mm = -1e30f; ss = 0.0f; }
    for (int j = j0; j < j0 + 256; ++j) {
      float4 p = sp[j];
      float dot = q.x*p.x + q.y*p.y + q.z*p.z;
      float dist = sqrtf(fmaxf((q.w + p.w) - 2.0f*dot, 0.0f));
      lse_add(mm, ss, fmaf(dist, SCNT, su[j]));
    }
    lse_merge(mm, ss, __shfl_xor(mm, 1), __shfl_xor(ss, 1));
    if (h == 0) r[row] = -(mm + __logf(ss));
    gbar(cnt, ++ep, t);
    // ---- col pass: c_j = -LSE_i(K_ij + r_i) incl pad row; 2 cols/block ----
    float m = -1e30f, s = 0.0f;
    for (int k = 0; k < 256; ++k) {
      int i = (k << 8) + tt;
      float4 qv = xyzs4[i];
      float ri = r[i];
      float dot = qv.x*pj.x + qv.y*pj.y + qv.z*pj.z;
      float dist = sqrtf(fmaxf((qv.w + pj.w) - 2.0f*dot, 0.0f));
      lse_add(m, s, fmaf(dist, SCNT, ri + g20));
    }
#pragma unroll
    for (int off = 32; off > 0; off >>= 1) {
      lse_merge(m, s, __shfl_down(m, off), __shfl_down(s, off));
    }
    if (lane == 0) red8[wid] = make_float2(m, s);
    __syncthreads();
    if (t == 0 || t == 256) {
      int w0 = (t >> 8) * 4;
      float M = red8[w0].x, S = red8[w0].y;
      for (int w = w0 + 1; w < w0 + 4; ++w) lse_merge(M, S, red8[w].x, red8[w].y);
      lse_merge(M, S, 0.0f, 1.0f);  // pad row
      c[jc] = -(M + __logf(S));
    }
    gbar(cnt, ++ep, t);
  }
}

// partial gamma^T @ feats : grid (64 n-chunks, 8 m-tiles), 128 threads
__global__ void k_pfeat_part(const float4* __restrict__ xyzs4,
                             const float4* __restrict__ pxyzs4,
                             const float* __restrict__ ge, const float* __restrict__ c,
                             const float* __restrict__ r, const float* __restrict__ feats,
                             float* __restrict__ part) {
  const int t = threadIdx.x;
  const int nc = blockIdx.x;
  const int mt = blockIdx.y;
  __shared__ float4 spp[64];
  __shared__ float  ssu[64];
  __shared__ float  sf[64][128];
  __shared__ float  sw[64][64];
  __shared__ float  srr[64];
  if (t < 64) {
    int j = mt*64 + t;
    spp[t] = pxyzs4[j];
    ssu[t] = fmaf(ge[j], NINV_TAU, c[j]);
  }
  const int mg = t >> 4;
  const int cg = t & 15;
  float acc[8][8];
#pragma unroll
  for (int a = 0; a < 8; ++a)
#pragma unroll
    for (int b = 0; b < 8; ++b) acc[a][b] = 0.0f;
  for (int bt = 0; bt < 16; ++bt) {
    int n0 = nc*1024 + bt*64;
    __syncthreads();
    for (int q2 = t; q2 < 2048; q2 += 128) {
      int row = q2 >> 5, c4 = q2 & 31;
      ((float4*)&sf[row][0])[c4] = ((const float4*)feats)[(size_t)(n0+row)*32 + c4];
    }
    if (t < 64) srr[t] = r[n0 + t];
    __syncthreads();
    for (int q2 = t; q2 < 4096; q2 += 128) {
      int nl = q2 >> 6, ml = q2 & 63;
      float4 qv = xyzs4[n0 + nl];
      float4 p = spp[ml];
      float dot = qv.x*p.x + qv.y*p.y + qv.z*p.z;
      float dist = sqrtf(fmaxf((qv.w + p.w) - 2.0f*dot, 0.0f));
      sw[nl][ml] = __expf(fmaf(dist, SCNT, ssu[ml] + srr[nl]));
    }
    __syncthreads();
#pragma unroll 8
    for (int n = 0; n < 64; ++n) {
      float4 w0 = ((float4*)&sw[n][0])[mg*2];
      float4 w1 = ((float4*)&sw[n][0])[mg*2+1];
      float4 f0 = ((float4*)&sf[n][0])[cg*2];
      float4 f1 = ((float4*)&sf[n][0])[cg*2+1];
      float wv[8] = {w0.x,w0.y,w0.z,w0.w,w1.x,w1.y,w1.z,w1.w};
      float fv[8] = {f0.x,f0.y,f0.z,f0.w,f1.x,f1.y,f1.z,f1.w};
#pragma unroll
      for (int a = 0; a < 8; ++a)
#pragma unroll
        for (int b = 0; b < 8; ++b) acc[a][b] = fmaf(wv[a], fv[b], acc[a][b]);
    }
  }
  for (int a = 0; a < 8; ++a) {
    int m = mt*64 + mg*8 + a;
    float* dst = &part[((size_t)nc*MP + m)*128 + cg*8];
    ((float4*)dst)[0] = make_float4(acc[a][0], acc[a][1], acc[a][2], acc[a][3]);
    ((float4*)dst)[1] = make_float4(acc[a][4], acc[a][5], acc[a][6], acc[a][7]);
  }
}

__global__ void k_pfeat_red(const float* __restrict__ part, const float* __restrict__ pf,
                            float* __restrict__ p1) {
  int idx = blockIdx.x*256 + threadIdx.x;
  float s = 0.0f;
  for (int ncb = 0; ncb < 64; ++ncb) s += part[(size_t)ncb*MP*128 + idx];
  p1[idx] = 0.5f*pf[idx] + 0.5f*s;
}

// sim column + top-20 aggregation -> p2
__global__ void k_simtopk(const float* __restrict__ p1, float* __restrict__ p2) {
  const int m = blockIdx.x, t = threadIdx.x;
  __shared__ float spm[128];
  __shared__ float scol[MP];
  __shared__ float sval[20];
  __shared__ int   sid[20];
  __shared__ float sredv[2];
  __shared__ int   sredi[2];
  __shared__ float sden;
  spm[t] = p1[m*128 + t];
  __syncthreads();
  for (int kk = t; kk < MP; kk += 128) {
    float a = 0.0f;
    const float* row = &p1[kk*128];
#pragma unroll 8
    for (int c2 = 0; c2 < 128; ++c2) a = fmaf(row[c2], spm[c2], a);
    scol[kk] = a * SCF;
  }
  __syncthreads();
  for (int rs = 0; rs < 20; ++rs) {
    float bv = -1e30f; int bI = 1 << 30;
    for (int kk = t; kk < MP; kk += 128) {
      float v = scol[kk];
      if (v > bv) { bv = v; bI = kk; }
    }
#pragma unroll
    for (int off = 32; off > 0; off >>= 1) {
      float ov = __shfl_down(bv, off); int oi = __shfl_down(bI, off);
      if (ov > bv || (ov == bv && oi < bI)) { bv = ov; bI = oi; }
    }
    if ((t & 63) == 0) { sredv[t>>6] = bv; sredi[t>>6] = bI; }
    __syncthreads();
    if (t == 0) {
      float v1 = sredv[1]; int i1 = sredi[1];
      if (v1 > bv || (v1 == bv && i1 < bI)) { bv = v1; bI = i1; }
      sval[rs] = bv; sid[rs] = bI;
      scol[bI] = -1e30f;
    }
    __syncthreads();
  }
  if (t == 0) {
    float s = 0.0f;
    for (int rs = 0; rs < 20; ++rs) s += sval[rs];
    sden = fmaxf(s, 1e-4f);
  }
  __syncthreads();
  float a = 0.0f;
  float den = sden;
  for (int rs = 0; rs < 20; ++rs) {
    float w = sval[rs] / den;
    a = fmaf(w, p1[sid[rs]*128 + t], a);
  }
  p2[m*128 + t] = 0.5f*p1[m*128 + t] + 0.5f*a;
}

// sim_pt = feats @ p2^T * sc (stored fp16) : grid (1024, 8), block 256
__global__ void k_simpt(const float* __restrict__ feats, const float* __restrict__ p2,
                        __half* __restrict__ sim) {
  const int t = threadIdx.x;
  const int nt = blockIdx.x;
  const int mt = blockIdx.y;
  __shared__ float sa[64][68];
  __shared__ float sb[64][68];
  const int tn = t >> 4, tm = t & 15;
  float acc[4][4];
#pragma unroll
  for (int x = 0; x < 4; ++x)
#pragma unroll
    for (int y = 0; y < 4; ++y) acc[x][y] = 0.0f;
  for (int kh = 0; kh < 2; ++kh) {
    __syncthreads();
    for (int q2 = t; q2 < 1024; q2 += 256) {
      int row = q2 >> 4, c4 = q2 & 15;
      ((float4*)&sa[row][0])[c4] =
          ((const float4*)feats)[(size_t)(nt*64+row)*32 + kh*16 + c4];
      ((float4*)&sb[row][0])[c4] =
          ((const float4*)p2)[(size_t)(mt*64+row)*32 + kh*16 + c4];
    }
    __syncthreads();
    for (int k = 0; k < 64; ++k) {
      float av[4], bv[4];
#pragma unroll
      for (int x = 0; x < 4; ++x) av[x] = sa[tn*4+x][k];
#pragma unroll
      for (int y = 0; y < 4; ++y) bv[y] = sb[tm*4+y][k];
#pragma unroll
      for (int x = 0; x < 4; ++x)
#pragma unroll
        for (int y = 0; y < 4; ++y) acc[x][y] = fmaf(av[x], bv[y], acc[x][y]);
    }
  }
  for (int x = 0; x < 4; ++x)
    for (int y = 0; y < 4; ++y) {
      int n = nt*64 + tn*4 + x, mc = mt*64 + tm*4 + y;
      sim[(size_t)n*MP + mc] = __float2half(acc[x][y] * SCF);
    }
}

// fused sinkhorn 2 over fp16 sim: 20 x (row; gbar; col-partial; gbar; reduce; gbar)
__global__ __launch_bounds__(512) void k_sk2(const __half* __restrict__ sim,
                                             float* __restrict__ r,
                                             float* __restrict__ c,
                                             float2* __restrict__ part,
                                             int* __restrict__ cnt) {
  const int t = threadIdx.x, b = blockIdx.x;
  __shared__ float scc[MP];
  __shared__ float sr[256];
  __shared__ float2 red8[8];
  int ep = 0;
  const int row = (b * 512 + t) >> 1, h = t & 1;
  const int lane = t & 63, wid = t >> 6;
  const int jc = 2 * b + (t >> 8), tt = t & 255;
  const us8* v8 = (const us8*)(sim + (size_t)row * MP + (h << 8));
  const int jb = h << 8;
  for (int it = 0; it < SKI; ++it) {
    scc[t] = it ? c[t] : 0.0f;
    __syncthreads();
    // ---- row pass ----
    float mm, ss;
    if (h == 0) { mm = 0.0f; ss = 1.0f; } else { mm = -1e30f; ss = 0.0f; }
    for (int g = 0; g < 32; ++g) {
      us8 u = v8[g];
#pragma unroll
      for (int e = 0; e < 8; ++e) {
        lse_add(mm, ss, fmaf(h2f(u[e]), NINV_TAU, scc[jb + g*8 + e]));
      }
    }
    lse_merge(mm, ss, __shfl_xor(mm, 1), __shfl_xor(ss, 1));
    if (h == 0) r[row] = -(mm + __logf(ss));
    gbar(cnt, ++ep, t);
    // ---- col partial: block b covers rows [b*256, b*256+256), col = t ----
    if (t < 256) sr[t] = r[b * 256 + t];
    __syncthreads();
    float m = -1e30f, s = 0.0f;
    for (int k = 0; k < 256; ++k) {
      float val = __half2float(sim[(size_t)(b * 256 + k) * MP + t]);
      lse_add(m, s, fmaf(val, NINV_TAU, sr[k]));
    }
    part[(size_t)b * MP + t] = make_float2(m, s);
    gbar(cnt, ++ep, t);
    // ---- reduce 256 partials per col; 2 cols/block ----
    float2 pv = part[(size_t)tt * MP + jc];
    float M = pv.x, S = pv.y;
#pragma unroll
    for (int off = 32; off > 0; off >>= 1) {
      lse_merge(M, S, __shfl_down(M, off), __shfl_down(S, off));
    }
    if (lane == 0) red8[wid] = make_float2(M, S);
    __syncthreads();
    if (t == 0 || t == 256) {
      int w0 = (t >> 8) * 4;
      float Mf = red8[w0].x, Sf = red8[w0].y;
      for (int w = w0 + 1; w < w0 + 4; ++w) lse_merge(Mf, Sf, red8[w].x, red8[w].y);
      lse_merge(Mf, Sf, 0.0f, 1.0f);  // pad row
      c[jc] = -(Mf + __logf(Sf));
    }
    gbar(cnt, ++ep, t);
  }
}

// refined = 0.5*feats + 0.5 * w @ p2  (w = exp(K + r + c) recomputed)
__global__ void k_refined(const __half* __restrict__ sim, const float* __restrict__ r,
                          const float* __restrict__ c, const float* __restrict__ p2,
                          const float* __restrict__ feats, float* __restrict__ out) {
  const int t = threadIdx.x;
  const int nb = blockIdx.x;  // 64 rows per block
  __shared__ float sp[64][128];
  __shared__ float sw[64][68];
  __shared__ float srr[64], scc[64];
  const int tn = t >> 5, tc = t & 31;
  if (t < 64) srr[t] = r[nb*64 + t];
  float acc[8][4];
#pragma unroll
  for (int a = 0; a < 8; ++a)
#pragma unroll
    for (int b = 0; b < 4; ++b) acc[a][b] = 0.0f;
  for (int mt2 = 0; mt2 < 8; ++mt2) {
    __syncthreads();
    for (int q2 = t; q2 < 2048; q2 += 256) {
      int row = q2 >> 5, c4 = q2 & 31;
      ((float4*)&sp[row][0])[c4] = ((const float4*)p2)[(size_t)(mt2*64+row)*32 + c4];
    }
    if (t < 64) scc[t] = c[mt2*64 + t];
    __syncthreads();
    for (int q2 = t; q2 < 4096; q2 += 256) {
      int nl = q2 >> 6, ml = q2 & 63;
      float val = __half2float(sim[(size_t)(nb*64+nl)*MP + mt2*64 + ml]);
      sw[nl][ml] = __expf(fmaf(val, NINV_TAU, srr[nl] + scc[ml]));
    }
    __syncthreads();
    for (int mm2 = 0; mm2 < 64; ++mm2) {
      float4 pv = ((float4*)&sp[mm2][0])[tc];
      float wv[8];
#pragma unroll
      for (int a = 0; a < 8; ++a) wv[a] = sw[tn*8+a][mm2];
#pragma unroll
      for (int a = 0; a < 8; ++a) {
        acc[a][0] = fmaf(wv[a], pv.x, acc[a][0]);
        acc[a][1] = fmaf(wv[a], pv.y, acc[a][1]);
        acc[a][2] = fmaf(wv[a], pv.z, acc[a][2]);
        acc[a][3] = fmaf(wv[a], pv.w, acc[a][3]);
      }
    }
  }
  for (int a = 0; a < 8; ++a) {
    int row = nb*64 + tn*8 + a;
    float4 f = ((const float4*)feats)[(size_t)row*32 + tc];
    float4 o;
    o.x = 0.5f*f.x + 0.5f*acc[a][0];
    o.y = 0.5f*f.y + 0.5f*acc[a][1];
    o.z = 0.5f*f.z + 0.5f*acc[a][2];
    o.w = 0.5f*f.w + 0.5f*acc[a][3];
    ((float4*)out)[(size_t)row*32 + tc] = o;
  }
}

// ---------------- launcher ----------------

extern "C" void kernel_launch(void* const* d_in, const int* in_sizes, int n_in,
                              void* d_out, int out_size, void* d_ws, size_t ws_size,
                              hipStream_t stream) {
  (void)in_sizes; (void)n_in; (void)out_size; (void)ws_size;
  const float* xyz   = (const float*)d_in[0];
  const float* feats = (const float*)d_in[1];
  float* out = (float*)d_out;
  char* ws = (char*)d_ws;

  auto al = [](size_t x) { return (x + 255) & ~(size_t)255; };
  // sim (fp16, 64MB) overlaps partA (float, 16.8MB): partA consumed before sim written
  __half* sim  = (__half*)ws;
  float* partA = (float*)ws;
  size_t o = al((size_t)NP * MP * 2);
  float4* xyzs4 = (float4*)(ws + o); o += al((size_t)NP * 16);
  float* rbuf   = (float*)(ws + o);  o += al((size_t)NP * 4);
  float* cbuf   = (float*)(ws + o);  o += al((size_t)MP * 4);
  int*   cent   = (int*)(ws + o);    o += al((size_t)MP * 4);
  float4* pxyzs4 = (float4*)(ws + o); o += al((size_t)MP * 16);
  float* ge     = (float*)(ws + o);  o += al((size_t)MP * 4);
  float* meann  = (float*)(ws + o);  o += al((size_t)256);
  float* pf     = (float*)(ws + o);  o += al((size_t)MP * 128 * 4);
  float* p1     = (float*)(ws + o);  o += al((size_t)MP * 128 * 4);
  float* p2     = (float*)(ws + o);  o += al((size_t)MP * 128 * 4);
  float2* part2 = (float2*)(ws + o); o += al((size_t)SKB * MP * 8);
  unsigned long long* fslots = (unsigned long long*)(ws + o);
  o += al((size_t)3 * FNB * 8);
  int* bar1 = (int*)(ws + o); o += al((size_t)256);
  int* bar2 = (int*)(ws + o); o += al((size_t)256);

  k_init<<<dim3(1), dim3(256), 0, stream>>>(fslots, bar1, bar2);
  k_prep<<<dim3(256), dim3(256), 0, stream>>>(xyz, xyzs4);
  k_fps3<<<dim3(FNB), dim3(256), 0, stream>>>(xyzs4, cent, fslots);
  k_gather1<<<dim3(1), dim3(512), 0, stream>>>(xyz, cent, pxyzs4, meann);
  k_gatherf<<<dim3(512), dim3(128), 0, stream>>>(feats, cent, pf);
  k_ballpca<<<dim3(512), dim3(256), 0, stream>>>(xyzs4, pxyzs4, meann, ge);

  k_sk1<<<dim3(SKB), dim3(512), 0, stream>>>(xyzs4, pxyzs4, ge, rbuf, cbuf, bar1);

  k_pfeat_part<<<dim3(64, 8), dim3(128), 0, stream>>>(xyzs4, pxyzs4, ge, cbuf, rbuf,
                                                      feats, partA);
  k_pfeat_red<<<dim3(256), dim3(256), 0, stream>>>(partA, pf, p1);
  k_simtopk<<<dim3(512), dim3(128), 0, stream>>>(p1, p2);

  k_simpt<<<dim3(1024, 8), dim3(256), 0, stream>>>(feats, p2, sim);
  k_sk2<<<dim3(SKB), dim3(512), 0, stream>>>(sim, rbuf, cbuf, part2, bar2);
  k_refined<<<dim3(1024), dim3(256), 0, stream>>>(sim, rbuf, cbuf, p2, feats, out);
}

// Round 5
// 11497.294 us; speedup vs baseline: 1.0496x; 1.0496x over previous
//
#include <hip/hip_runtime.h>
#include <hip/hip_fp16.h>
#include <math.h>

#define NP 65536
#define MP 512
#define SKI 20
#define NBALL 10

#define FNB 16      // fps blocks (slots fit one cache line)
#define SKB 256     // sinkhorn blocks

// f32(-1/0.05f) rounds exactly to -20.0f
#define NINV_TAU (-20.0f)
// 1/f32(sqrt(128)) ; sc = 1/sqrt(C)
#define SCF (1.0f / 11.313708305358886719f)
#define SCNT (SCF * NINV_TAU)

typedef unsigned short us8 __attribute__((ext_vector_type(8)));

// ---------------- helpers ----------------

__device__ __forceinline__ float h2f(unsigned short u) {
  return __half2float(__builtin_bit_cast(__half, u));
}

// branchless online LSE update: bit-identical to the branchy version
// (exp(0)==1.0f exactly, fmaf(x,1,y)==x+y exactly) but straight-line code
// so the compiler can pipeline surrounding loads.
__device__ __forceinline__ void lse_add(float& mm, float& ss, float v) {
  float nm = fmaxf(mm, v);
  ss = fmaf(ss, __expf(mm - nm), __expf(v - nm));
  mm = nm;
}
__device__ __forceinline__ void lse_merge(float& mm, float& ss, float om, float os) {
  float nm = fmaxf(mm, om);
  ss = ss * __expf(mm - nm) + os * __expf(om - nm);
  mm = nm;
}

// global barrier: single monotonic counter, one FAA + one poller per block.
__device__ __forceinline__ void gbar(int* cnt, int ep, int t) {
  __syncthreads();
  if (t == 0) {
    __threadfence();
    __hip_atomic_fetch_add(cnt, 1, __ATOMIC_RELEASE, __HIP_MEMORY_SCOPE_AGENT);
    while (__hip_atomic_load(cnt, __ATOMIC_ACQUIRE, __HIP_MEMORY_SCOPE_AGENT) <
           ep * SKB) {
      __builtin_amdgcn_s_sleep(1);
    }
  }
  __syncthreads();
  __threadfence();
}

// closed-form symmetric 3x3 eigenvalues (ascending), double precision
__device__ void eig3(double a00, double a01, double a02, double a11, double a12,
                     double a22, double* e) {
  double p1 = a01*a01 + a02*a02 + a12*a12;
  double q  = (a00 + a11 + a22) / 3.0;
  double b00 = a00 - q, b11 = a11 - q, b22 = a22 - q;
  double p2 = b00*b00 + b11*b11 + b22*b22 + 2.0*p1;
  if (p2 <= 1e-300) { e[0] = e[1] = e[2] = q; return; }
  double p = sqrt(p2 / 6.0);
  double ip = 1.0 / p;
  double c00 = b00*ip, c01 = a01*ip, c02 = a02*ip;
  double c11 = b11*ip, c12 = a12*ip, c22 = b22*ip;
  double detB = c00*(c11*c22 - c12*c12) - c01*(c01*c22 - c12*c02)
              + c02*(c01*c12 - c11*c02);
  double r = detB / 2.0;
  r = fmin(1.0, fmax(-1.0, r));
  double phi = acos(r) / 3.0;
  double e2 = q + 2.0*p*cos(phi);
  double e0 = q + 2.0*p*cos(phi + 2.0943951023931953);
  double e1 = 3.0*q - e2 - e0;
  e[0] = e0; e[1] = e1; e[2] = e2;
}

// ---------------- kernels ----------------

__global__ void k_init(unsigned long long* __restrict__ slots, int* __restrict__ bar1,
                       int* __restrict__ bar2) {
  int t = threadIdx.x;
  if (t < 3 * FNB) slots[t] = 0ULL;
  if (t < 64) { bar1[t] = 0; bar2[t] = 0; }
}

// pack xyz + |x|^2 into float4
__global__ void k_prep(const float* __restrict__ xyz, float4* __restrict__ xyzs4) {
  int i = blockIdx.x * blockDim.x + threadIdx.x;
  if (i < NP) {
    float x = xyz[3*i+0], y = xyz[3*i+1], z = xyz[3*i+2];
    xyzs4[i] = make_float4(x, y, z, x*x + y*y + z*z);
  }
}

// FPS: 16 blocks x 256 threads, 16 pts/thread in regs. Payload-carrying slot
// barrier (one cache line per phase), mod-3 phase buffering.
__global__ __launch_bounds__(256) void k_fps3(const float4* __restrict__ xyzs4,
                                              int* __restrict__ cent,
                                              unsigned long long* __restrict__ slots) {
  const int t = threadIdx.x, b = blockIdx.x;
  const int base = (b * 256 + t) * 16;
  float X[16], Y[16], Z[16], D[16];
#pragma unroll
  for (int k = 0; k < 16; ++k) {
    float4 p = xyzs4[base + k];
    X[k] = p.x; Y[k] = p.y; Z[k] = p.z; D[k] = 1e10f;
  }
  __shared__ unsigned long long swave[4];
  __shared__ unsigned long long swin;
  int cur = 0;
  float cx = xyzs4[0].x, cy = xyzs4[0].y, cz = xyzs4[0].z;
  const int lane = t & 63, wid = t >> 6;
  for (int it = 0; it < MP; ++it) {
    if (b == 0 && t == 0) cent[it] = cur;
    float bm = -1.0f; int bi = 0x7fffffff;
#pragma unroll
    for (int k = 0; k < 16; ++k) {
      float dx = X[k] - cx, dy = Y[k] - cy, dz = Z[k] - cz;
      float d = dx*dx + dy*dy + dz*dz;
      float nd = fminf(D[k], d);
      D[k] = nd;
      bool gt = (nd > bm);
      bi = gt ? (base + k) : bi;
      bm = gt ? nd : bm;
    }
    unsigned long long key =
        ((unsigned long long)__float_as_uint(bm) << 32) |
        (unsigned int)(0x7fffffff - bi);
#pragma unroll
    for (int off = 32; off > 0; off >>= 1) {
      unsigned long long o = __shfl_down(key, off);
      key = (o > key) ? o : key;
    }
    if (lane == 0) swave[wid] = key;
    __syncthreads();
    const int p = it % 3, pn = (it + 1) % 3;
    if (t == 0) {
      unsigned long long k0 = swave[0];
      for (int w = 1; w < 4; ++w) k0 = (swave[w] > k0) ? swave[w] : k0;
      __hip_atomic_store(&slots[pn * FNB + b], 0ULL, __ATOMIC_RELAXED,
                         __HIP_MEMORY_SCOPE_AGENT);
      __hip_atomic_store(&slots[p * FNB + b], k0, __ATOMIC_RELEASE,
                         __HIP_MEMORY_SCOPE_AGENT);
    }
    if (wid == 0) {
      unsigned long long v = 0ULL;
      if (lane < FNB) {
        do {
          v = __hip_atomic_load(&slots[p * FNB + lane], __ATOMIC_ACQUIRE,
                                __HIP_MEMORY_SCOPE_AGENT);
        } while (v == 0ULL);
      }
#pragma unroll
      for (int off = 32; off > 0; off >>= 1) {
        unsigned long long o = __shfl_down(v, off);
        v = (o > v) ? o : v;
      }
      if (lane == 0) swin = v;
    }
    __syncthreads();
    unsigned long long wkey = swin;
    cur = 0x7fffffff - (int)(wkey & 0xffffffffu);
    float4 cc = xyzs4[cur];
    cx = cc.x; cy = cc.y; cz = cc.z;
    __syncthreads();
  }
}

// gather proto xyz (+norm) and mean node
__global__ void k_gather1(const float* __restrict__ xyz, const int* __restrict__ cent,
                          float4* __restrict__ pxyzs4, float* __restrict__ meann) {
  __shared__ float sx[512], sy[512], sz[512];
  int m = threadIdx.x;
  int c = cent[m];
  float x = xyz[3*c+0], y = xyz[3*c+1], z = xyz[3*c+2];
  pxyzs4[m] = make_float4(x, y, z, x*x + y*y + z*z);
  sx[m] = x; sy[m] = y; sz[m] = z;
  __syncthreads();
  for (int off = 256; off > 0; off >>= 1) {
    if (m < off) { sx[m] += sx[m+off]; sy[m] += sy[m+off]; sz[m] += sz[m+off]; }
    __syncthreads();
  }
  if (m == 0) {
    meann[0] = sx[0] * (1.0f/512.0f);
    meann[1] = sy[0] * (1.0f/512.0f);
    meann[2] = sz[0] * (1.0f/512.0f);
  }
}

// gather proto features
__global__ void k_gatherf(const float* __restrict__ feats, const int* __restrict__ cent,
                          float* __restrict__ pf) {
  int m = blockIdx.x, c = threadIdx.x;
  pf[m*128 + c] = feats[(size_t)cent[m]*128 + c];
}

// ball query (first 10 smallest indices within radius) + PCA curvature -> dist_ge
__global__ void k_ballpca(const float4* __restrict__ xyzs4,
                          const float4* __restrict__ pxyzs4,
                          const float* __restrict__ meann,
                          float* __restrict__ ge) {
  const int m = blockIdx.x, t = threadIdx.x;
  __shared__ int lidx[256][NBALL];
  __shared__ int s_sel[NBALL];
  __shared__ int s_win;
  __shared__ int s_w4[4];
  float4 q = pxyzs4[m];
  int cnt = 0;
  for (int k = 0; k < 256; ++k) {
    int i = (k << 8) + t;
    float4 p = xyzs4[i];
    float dot = q.x*p.x + q.y*p.y + q.z*p.z;
    float d2 = (q.w + p.w) - 2.0f*dot;
    float d = sqrtf(fmaxf(d2, 0.0f));
    if (!(d > 0.04f) && cnt < NBALL) { lidx[t][cnt] = i; cnt++; }
  }
  __syncthreads();
  int hp = 0;
  for (int r = 0; r < NBALL; ++r) {
    int v = (hp < cnt) ? lidx[t][hp] : 0x7fffffff;
#pragma unroll
    for (int off = 32; off > 0; off >>= 1) v = min(v, __shfl_down(v, off));
    if ((t & 63) == 0) s_w4[t >> 6] = v;
    __syncthreads();
    if (t == 0) s_win = min(min(s_w4[0], s_w4[1]), min(s_w4[2], s_w4[3]));
    __syncthreads();
    int w = s_win;
    if (w != 0x7fffffff && hp < cnt && lidx[t][hp] == w) hp++;
    if (t == 0) s_sel[r] = w;
    __syncthreads();
  }
  if (t == 0) {
    float mx = meann[0], my = meann[1], mz = meann[2];
    int first = (s_sel[0] != 0x7fffffff) ? s_sel[0] : NP;
    float c00=0,c01=0,c02=0,c11=0,c12=0,c22=0;
    for (int r = 0; r < NBALL; ++r) {
      int id = s_sel[r];
      if (id == 0x7fffffff) id = first;
      float nx, ny, nz;
      if (id >= NP) { nx = mx; ny = my; nz = mz; }
      else { float4 p = xyzs4[id]; nx = p.x; ny = p.y; nz = p.z; }
      float dx = nx - q.x, dy = ny - q.y, dz = nz - q.z;
      c00 += dx*dx; c01 += dx*dy; c02 += dx*dz;
      c11 += dy*dy; c12 += dy*dz; c22 += dz*dz;
    }
    double e[3];
    eig3((double)(c00/10.0f + 1e-8f), (double)(c01/10.0f + 1e-8f),
         (double)(c02/10.0f + 1e-8f), (double)(c11/10.0f + 1e-8f),
         (double)(c12/10.0f + 1e-8f), (double)(c22/10.0f + 1e-8f), e);
    float l0 = (float)e[0], l1 = (float)e[1], l2r = (float)e[2];
    float l2 = fmaxf(l2r, 1e-8f);
    float f0 = (l2 - l1) / l2, f1 = (l1 - l0) / l2, f2 = l0 / l2;
    ge[m] = sqrtf(f0*f0 + f1*f1 + f2*f2) / sqrtf(3.0f);
  }
}

// fused sinkhorn 1: 256 blocks x 1024 threads persistent.
// row: 4 lanes/row over LDS-staged protos; col: 512 lanes/col over xyzs4.
__global__ __launch_bounds__(1024) void k_sk1(const float4* __restrict__ xyzs4,
                                              const float4* __restrict__ pxyzs4,
                                              const float* __restrict__ ge,
                                              float* __restrict__ r,
                                              float* __restrict__ c,
                                              int* __restrict__ cnt) {
  const int t = threadIdx.x, b = blockIdx.x;
  __shared__ float4 sp[MP];
  __shared__ float  su[MP];
  __shared__ float2 red16[16];
  int ep = 0;
  const int row = b * 256 + (t >> 2), q = t & 3;
  const int lane = t & 63, wid = t >> 6;
  const int jc = 2 * b + (t >> 9), tt = t & 511;
  if (t < MP) sp[t] = pxyzs4[t];
  const float4 qv = xyzs4[row];
  const float4 pj = pxyzs4[jc];
  const float g20 = ge[jc] * NINV_TAU;
  __syncthreads();
  for (int it = 0; it < SKI; ++it) {
    if (t < MP) su[t] = fmaf(ge[t], NINV_TAU, it ? c[t] : 0.0f);
    __syncthreads();
    // ---- row pass: r_i = -LSE_j(K_ij + c_j), 128 protos per lane ----
    float mm, ss;
    if (q == 0) { mm = 0.0f; ss = 1.0f; } else { mm = -1e30f; ss = 0.0f; }
    const int j0 = q << 7;
    for (int j = j0; j < j0 + 128; ++j) {
      float4 p = sp[j];
      float dot = qv.x*p.x + qv.y*p.y + qv.z*p.z;
      float dist = sqrtf(fmaxf((qv.w + p.w) - 2.0f*dot, 0.0f));
      lse_add(mm, ss, fmaf(dist, SCNT, su[j]));
    }
    lse_merge(mm, ss, __shfl_xor(mm, 1), __shfl_xor(ss, 1));
    lse_merge(mm, ss, __shfl_xor(mm, 2), __shfl_xor(ss, 2));
    if (q == 0) r[row] = -(mm + __logf(ss));
    gbar(cnt, ++ep, t);
    // ---- col pass: 2 cols/block, 512 lanes/col, 128 pts/lane, batched ----
    float m = -1e30f, s = 0.0f;
    for (int k0 = 0; k0 < 128; k0 += 4) {
      float4 pv[4]; float rv[4];
#pragma unroll
      for (int u = 0; u < 4; ++u) {
        int i = ((k0 + u) << 9) + tt;
        pv[u] = xyzs4[i];
        rv[u] = r[i];
      }
#pragma unroll
      for (int u = 0; u < 4; ++u) {
        float dot = pv[u].x*pj.x + pv[u].y*pj.y + pv[u].z*pj.z;
        float dist = sqrtf(fmaxf((pv[u].w + pj.w) - 2.0f*dot, 0.0f));
        lse_add(m, s, fmaf(dist, SCNT, rv[u] + g20));
      }
    }
#pragma unroll
    for (int off = 32; off > 0; off >>= 1) {
      lse_merge(m, s, __shfl_down(m, off), __shfl_down(s, off));
    }
    if (lane == 0) red16[wid] = make_float2(m, s);
    __syncthreads();
    if (t == 0 || t == 512) {
      int w0 = (t >> 9) * 8;
      float M = red16[w0].x, S = red16[w0].y;
      for (int w = w0 + 1; w < w0 + 8; ++w) lse_merge(M, S, red16[w].x, red16[w].y);
      lse_merge(M, S, 0.0f, 1.0f);  // pad row
      c[jc] = -(M + __logf(S));
    }
    gbar(cnt, ++ep, t);
  }
}

// partial gamma^T @ feats : grid (64 n-chunks, 8 m-tiles), 128 threads
__global__ void k_pfeat_part(const float4* __restrict__ xyzs4,
                             const float4* __restrict__ pxyzs4,
                             const float* __restrict__ ge, const float* __restrict__ c,
                             const float* __restrict__ r, const float* __restrict__ feats,
                             float* __restrict__ part) {
  const int t = threadIdx.x;
  const int nc = blockIdx.x;
  const int mt = blockIdx.y;
  __shared__ float4 spp[64];
  __shared__ float  ssu[64];
  __shared__ float  sf[64][128];
  __shared__ float  sw[64][64];
  __shared__ float  srr[64];
  if (t < 64) {
    int j = mt*64 + t;
    spp[t] = pxyzs4[j];
    ssu[t] = fmaf(ge[j], NINV_TAU, c[j]);
  }
  const int mg = t >> 4;
  const int cg = t & 15;
  float acc[8][8];
#pragma unroll
  for (int a = 0; a < 8; ++a)
#pragma unroll
    for (int b = 0; b < 8; ++b) acc[a][b] = 0.0f;
  for (int bt = 0; bt < 16; ++bt) {
    int n0 = nc*1024 + bt*64;
    __syncthreads();
    for (int q2 = t; q2 < 2048; q2 += 128) {
      int row = q2 >> 5, c4 = q2 & 31;
      ((float4*)&sf[row][0])[c4] = ((const float4*)feats)[(size_t)(n0+row)*32 + c4];
    }
    if (t < 64) srr[t] = r[n0 + t];
    __syncthreads();
    for (int q2 = t; q2 < 4096; q2 += 128) {
      int nl = q2 >> 6, ml = q2 & 63;
      float4 qv = xyzs4[n0 + nl];
      float4 p = spp[ml];
      float dot = qv.x*p.x + qv.y*p.y + qv.z*p.z;
      float dist = sqrtf(fmaxf((qv.w + p.w) - 2.0f*dot, 0.0f));
      sw[nl][ml] = __expf(fmaf(dist, SCNT, ssu[ml] + srr[nl]));
    }
    __syncthreads();
#pragma unroll 8
    for (int n = 0; n < 64; ++n) {
      float4 w0 = ((float4*)&sw[n][0])[mg*2];
      float4 w1 = ((float4*)&sw[n][0])[mg*2+1];
      float4 f0 = ((float4*)&sf[n][0])[cg*2];
      float4 f1 = ((float4*)&sf[n][0])[cg*2+1];
      float wv[8] = {w0.x,w0.y,w0.z,w0.w,w1.x,w1.y,w1.z,w1.w};
      float fv[8] = {f0.x,f0.y,f0.z,f0.w,f1.x,f1.y,f1.z,f1.w};
#pragma unroll
      for (int a = 0; a < 8; ++a)
#pragma unroll
        for (int b = 0; b < 8; ++b) acc[a][b] = fmaf(wv[a], fv[b], acc[a][b]);
    }
  }
  for (int a = 0; a < 8; ++a) {
    int m = mt*64 + mg*8 + a;
    float* dst = &part[((size_t)nc*MP + m)*128 + cg*8];
    ((float4*)dst)[0] = make_float4(acc[a][0], acc[a][1], acc[a][2], acc[a][3]);
    ((float4*)dst)[1] = make_float4(acc[a][4], acc[a][5], acc[a][6], acc[a][7]);
  }
}

__global__ void k_pfeat_red(const float* __restrict__ part, const float* __restrict__ pf,
                            float* __restrict__ p1) {
  int idx = blockIdx.x*256 + threadIdx.x;
  float s = 0.0f;
  for (int ncb = 0; ncb < 64; ++ncb) s += part[(size_t)ncb*MP*128 + idx];
  p1[idx] = 0.5f*pf[idx] + 0.5f*s;
}

// sim column + top-20 aggregation -> p2
__global__ void k_simtopk(const float* __restrict__ p1, float* __restrict__ p2) {
  const int m = blockIdx.x, t = threadIdx.x;
  __shared__ float spm[128];
  __shared__ float scol[MP];
  __shared__ float sval[20];
  __shared__ int   sid[20];
  __shared__ float sredv[2];
  __shared__ int   sredi[2];
  __shared__ float sden;
  spm[t] = p1[m*128 + t];
  __syncthreads();
  for (int kk = t; kk < MP; kk += 128) {
    float a = 0.0f;
    const float* row = &p1[kk*128];
#pragma unroll 8
    for (int c2 = 0; c2 < 128; ++c2) a = fmaf(row[c2], spm[c2], a);
    scol[kk] = a * SCF;
  }
  __syncthreads();
  for (int rs = 0; rs < 20; ++rs) {
    float bv = -1e30f; int bI = 1 << 30;
    for (int kk = t; kk < MP; kk += 128) {
      float v = scol[kk];
      if (v > bv) { bv = v; bI = kk; }
    }
#pragma unroll
    for (int off = 32; off > 0; off >>= 1) {
      float ov = __shfl_down(bv, off); int oi = __shfl_down(bI, off);
      if (ov > bv || (ov == bv && oi < bI)) { bv = ov; bI = oi; }
    }
    if ((t & 63) == 0) { sredv[t>>6] = bv; sredi[t>>6] = bI; }
    __syncthreads();
    if (t == 0) {
      float v1 = sredv[1]; int i1 = sredi[1];
      if (v1 > bv || (v1 == bv && i1 < bI)) { bv = v1; bI = i1; }
      sval[rs] = bv; sid[rs] = bI;
      scol[bI] = -1e30f;
    }
    __syncthreads();
  }
  if (t == 0) {
    float s = 0.0f;
    for (int rs = 0; rs < 20; ++rs) s += sval[rs];
    sden = fmaxf(s, 1e-4f);
  }
  __syncthreads();
  float a = 0.0f;
  float den = sden;
  for (int rs = 0; rs < 20; ++rs) {
    float w = sval[rs] / den;
    a = fmaf(w, p1[sid[rs]*128 + t], a);
  }
  p2[m*128 + t] = 0.5f*p1[m*128 + t] + 0.5f*a;
}

// sim_pt = feats @ p2^T * sc (stored fp16) : grid (1024, 8), block 256
__global__ void k_simpt(const float* __restrict__ feats, const float* __restrict__ p2,
                        __half* __restrict__ sim) {
  const int t = threadIdx.x;
  const int nt = blockIdx.x;
  const int mt = blockIdx.y;
  __shared__ float sa[64][68];
  __shared__ float sb[64][68];
  const int tn = t >> 4, tm = t & 15;
  float acc[4][4];
#pragma unroll
  for (int x = 0; x < 4; ++x)
#pragma unroll
    for (int y = 0; y < 4; ++y) acc[x][y] = 0.0f;
  for (int kh = 0; kh < 2; ++kh) {
    __syncthreads();
    for (int q2 = t; q2 < 1024; q2 += 256) {
      int row = q2 >> 4, c4 = q2 & 15;
      ((float4*)&sa[row][0])[c4] =
          ((const float4*)feats)[(size_t)(nt*64+row)*32 + kh*16 + c4];
      ((float4*)&sb[row][0])[c4] =
          ((const float4*)p2)[(size_t)(mt*64+row)*32 + kh*16 + c4];
    }
    __syncthreads();
    for (int k = 0; k < 64; ++k) {
      float av[4], bv[4];
#pragma unroll
      for (int x = 0; x < 4; ++x) av[x] = sa[tn*4+x][k];
#pragma unroll
      for (int y = 0; y < 4; ++y) bv[y] = sb[tm*4+y][k];
#pragma unroll
      for (int x = 0; x < 4; ++x)
#pragma unroll
        for (int y = 0; y < 4; ++y) acc[x][y] = fmaf(av[x], bv[y], acc[x][y]);
    }
  }
  for (int x = 0; x < 4; ++x)
    for (int y = 0; y < 4; ++y) {
      int n = nt*64 + tn*4 + x, mc = mt*64 + tm*4 + y;
      sim[(size_t)n*MP + mc] = __float2half(acc[x][y] * SCF);
    }
}

// fused sinkhorn 2 over fp16 sim: 256 blocks x 1024 threads.
// row: 4 lanes/row, batched us8 loads; col: 512 cols x 2 row-halves, batched.
__global__ __launch_bounds__(1024) void k_sk2(const __half* __restrict__ sim,
                                              float* __restrict__ r,
                                              float* __restrict__ c,
                                              float2* __restrict__ part,
                                              int* __restrict__ cnt) {
  const int t = threadIdx.x, b = blockIdx.x;
  __shared__ float scc[MP];
  __shared__ float sr[256];
  __shared__ float2 smrg[MP];
  __shared__ float2 red8[8];
  int ep = 0;
  const int row = b * 256 + (t >> 2), q = t & 3;
  const int lane = t & 63, wid = t >> 6;
  const us8* v8 = (const us8*)(sim + (size_t)row * MP + (q << 7));
  const int jb = q << 7;
  const int ct = t & 511, rh = t >> 9;          // col pass: col, row-half
  const int jc = 2 * b + (t >> 8), tt = t & 255; // reduce: 2 cols/block (t<512)
  for (int it = 0; it < SKI; ++it) {
    if (t < MP) scc[t] = it ? c[t] : 0.0f;
    __syncthreads();
    // ---- row pass: 128 cols per lane, 8-deep batched us8 loads ----
    float mm, ss;
    if (q == 0) { mm = 0.0f; ss = 1.0f; } else { mm = -1e30f; ss = 0.0f; }
    for (int half = 0; half < 2; ++half) {
      us8 u[8];
#pragma unroll
      for (int g = 0; g < 8; ++g) u[g] = v8[half*8 + g];
#pragma unroll
      for (int g = 0; g < 8; ++g)
#pragma unroll
        for (int e = 0; e < 8; ++e) {
          lse_add(mm, ss, fmaf(h2f(u[g][e]), NINV_TAU, scc[jb + half*64 + g*8 + e]));
        }
    }
    lse_merge(mm, ss, __shfl_xor(mm, 1), __shfl_xor(ss, 1));
    lse_merge(mm, ss, __shfl_xor(mm, 2), __shfl_xor(ss, 2));
    if (q == 0) r[row] = -(mm + __logf(ss));
    gbar(cnt, ++ep, t);
    // ---- col partial: rows [b*256+rh*128, +128) for col ct, 8-deep batch ----
    if (t < 256) sr[t] = r[b * 256 + t];
    __syncthreads();
    float m = -1e30f, s = 0.0f;
    const int r0 = rh * 128;
    for (int k0 = 0; k0 < 128; k0 += 8) {
      float v[8];
#pragma unroll
      for (int u2 = 0; u2 < 8; ++u2)
        v[u2] = __half2float(sim[(size_t)(b*256 + r0 + k0 + u2) * MP + ct]);
#pragma unroll
      for (int u2 = 0; u2 < 8; ++u2)
        lse_add(m, s, fmaf(v[u2], NINV_TAU, sr[r0 + k0 + u2]));
    }
    if (rh == 1) smrg[ct] = make_float2(m, s);
    __syncthreads();
    if (rh == 0) {
      float2 o = smrg[ct];
      lse_merge(m, s, o.x, o.y);
      part[(size_t)b * MP + ct] = make_float2(m, s);
    }
    gbar(cnt, ++ep, t);
    // ---- reduce 256 partials per col; 2 cols/block (threads < 512) ----
    float M = -1e30f, S = 0.0f;
    if (t < 512) {
      float2 pv = part[(size_t)tt * MP + jc];
      M = pv.x; S = pv.y;
#pragma unroll
      for (int off = 32; off > 0; off >>= 1) {
        lse_merge(M, S, __shfl_down(M, off), __shfl_down(S, off));
      }
      if (lane == 0) red8[wid] = make_float2(M, S);
    }
    __syncthreads();
    if (t == 0 || t == 256) {
      int w0 = (t >> 8) * 4;
      float Mf = red8[w0].x, Sf = red8[w0].y;
      for (int w = w0 + 1; w < w0 + 4; ++w) lse_merge(Mf, Sf, red8[w].x, red8[w].y);
      lse_merge(Mf, Sf, 0.0f, 1.0f);  // pad row
      c[jc] = -(Mf + __logf(Sf));
    }
    gbar(cnt, ++ep, t);
  }
}

// refined = 0.5*feats + 0.5 * w @ p2  (w = exp(K + r + c) recomputed)
__global__ void k_refined(const __half* __restrict__ sim, const float* __restrict__ r,
                          const float* __restrict__ c, const float* __restrict__ p2,
                          const float* __restrict__ feats, float* __restrict__ out) {
  const int t = threadIdx.x;
  const int nb = blockIdx.x;  // 64 rows per block
  __shared__ float sp[64][128];
  __shared__ float sw[64][68];
  __shared__ float srr[64], scc[64];
  const int tn = t >> 5, tc = t & 31;
  if (t < 64) srr[t] = r[nb*64 + t];
  float acc[8][4];
#pragma unroll
  for (int a = 0; a < 8; ++a)
#pragma unroll
    for (int b = 0; b < 4; ++b) acc[a][b] = 0.0f;
  for (int mt2 = 0; mt2 < 8; ++mt2) {
    __syncthreads();
    for (int q2 = t; q2 < 2048; q2 += 256) {
      int row = q2 >> 5, c4 = q2 & 31;
      ((float4*)&sp[row][0])[c4] = ((const float4*)p2)[(size_t)(mt2*64+row)*32 + c4];
    }
    if (t < 64) scc[t] = c[mt2*64 + t];
    __syncthreads();
    for (int q2 = t; q2 < 4096; q2 += 256) {
      int nl = q2 >> 6, ml = q2 & 63;
      float val = __half2float(sim[(size_t)(nb*64+nl)*MP + mt2*64 + ml]);
      sw[nl][ml] = __expf(fmaf(val, NINV_TAU, srr[nl] + scc[ml]));
    }
    __syncthreads();
    for (int mm2 = 0; mm2 < 64; ++mm2) {
      float4 pv = ((float4*)&sp[mm2][0])[tc];
      float wv[8];
#pragma unroll
      for (int a = 0; a < 8; ++a) wv[a] = sw[tn*8+a][mm2];
#pragma unroll
      for (int a = 0; a < 8; ++a) {
        acc[a][0] = fmaf(wv[a], pv.x, acc[a][0]);
        acc[a][1] = fmaf(wv[a], pv.y, acc[a][1]);
        acc[a][2] = fmaf(wv[a], pv.z, acc[a][2]);
        acc[a][3] = fmaf(wv[a], pv.w, acc[a][3]);
      }
    }
  }
  for (int a = 0; a < 8; ++a) {
    int row = nb*64 + tn*8 + a;
    float4 f = ((const float4*)feats)[(size_t)row*32 + tc];
    float4 o;
    o.x = 0.5f*f.x + 0.5f*acc[a][0];
    o.y = 0.5f*f.y + 0.5f*acc[a][1];
    o.z = 0.5f*f.z + 0.5f*acc[a][2];
    o.w = 0.5f*f.w + 0.5f*acc[a][3];
    ((float4*)out)[(size_t)row*32 + tc] = o;
  }
}

// ---------------- launcher ----------------

extern "C" void kernel_launch(void* const* d_in, const int* in_sizes, int n_in,
                              void* d_out, int out_size, void* d_ws, size_t ws_size,
                              hipStream_t stream) {
  (void)in_sizes; (void)n_in; (void)out_size; (void)ws_size;
  const float* xyz   = (const float*)d_in[0];
  const float* feats = (const float*)d_in[1];
  float* out = (float*)d_out;
  char* ws = (char*)d_ws;

  auto al = [](size_t x) { return (x + 255) & ~(size_t)255; };
  // sim (fp16, 64MB) overlaps partA (float, 16.8MB): partA consumed before sim written
  __half* sim  = (__half*)ws;
  float* partA = (float*)ws;
  size_t o = al((size_t)NP * MP * 2);
  float4* xyzs4 = (float4*)(ws + o); o += al((size_t)NP * 16);
  float* rbuf   = (float*)(ws + o);  o += al((size_t)NP * 4);
  float* cbuf   = (float*)(ws + o);  o += al((size_t)MP * 4);
  int*   cent   = (int*)(ws + o);    o += al((size_t)MP * 4);
  float4* pxyzs4 = (float4*)(ws + o); o += al((size_t)MP * 16);
  float* ge     = (float*)(ws + o);  o += al((size_t)MP * 4);
  float* meann  = (float*)(ws + o);  o += al((size_t)256);
  float* pf     = (float*)(ws + o);  o += al((size_t)MP * 128 * 4);
  float* p1     = (float*)(ws + o);  o += al((size_t)MP * 128 * 4);
  float* p2     = (float*)(ws + o);  o += al((size_t)MP * 128 * 4);
  float2* part2 = (float2*)(ws + o); o += al((size_t)SKB * MP * 8);
  unsigned long long* fslots = (unsigned long long*)(ws + o);
  o += al((size_t)3 * FNB * 8);
  int* bar1 = (int*)(ws + o); o += al((size_t)256);
  int* bar2 = (int*)(ws + o); o += al((size_t)256);

  k_init<<<dim3(1), dim3(256), 0, stream>>>(fslots, bar1, bar2);
  k_prep<<<dim3(256), dim3(256), 0, stream>>>(xyz, xyzs4);
  k_fps3<<<dim3(FNB), dim3(256), 0, stream>>>(xyzs4, cent, fslots);
  k_gather1<<<dim3(1), dim3(512), 0, stream>>>(xyz, cent, pxyzs4, meann);
  k_gatherf<<<dim3(512), dim3(128), 0, stream>>>(feats, cent, pf);
  k_ballpca<<<dim3(512), dim3(256), 0, stream>>>(xyzs4, pxyzs4, meann, ge);

  k_sk1<<<dim3(SKB), dim3(1024), 0, stream>>>(xyzs4, pxyzs4, ge, rbuf, cbuf, bar1);

  k_pfeat_part<<<dim3(64, 8), dim3(128), 0, stream>>>(xyzs4, pxyzs4, ge, cbuf, rbuf,
                                                      feats, partA);
  k_pfeat_red<<<dim3(256), dim3(256), 0, stream>>>(partA, pf, p1);
  k_simtopk<<<dim3(512), dim3(128), 0, stream>>>(p1, p2);

  k_simpt<<<dim3(1024, 8), dim3(256), 0, stream>>>(feats, p2, sim);
  k_sk2<<<dim3(SKB), dim3(1024), 0, stream>>>(sim, rbuf, cbuf, part2, bar2);
  k_refined<<<dim3(1024), dim3(256), 0, stream>>>(sim, rbuf, cbuf, p2, feats, out);
}

// Round 6
// 10878.897 us; speedup vs baseline: 1.1093x; 1.0568x over previous
//
#include <hip/hip_runtime.h>
#include <hip/hip_fp16.h>
#include <math.h>

#define NP 65536
#define MP 512
#define SKI 20
#define NBALL 10

#define FNB 8       // fps blocks (slots fit one cache line)
#define SKB 64      // sinkhorn blocks (low barrier fan-in)

// f32(-1/0.05f) rounds exactly to -20.0f
#define NINV_TAU (-20.0f)
// 1/f32(sqrt(128)) ; sc = 1/sqrt(C)
#define SCF (1.0f / 11.313708305358886719f)
#define SCNT (SCF * NINV_TAU)

typedef unsigned short us8 __attribute__((ext_vector_type(8)));

// ---------------- helpers ----------------

__device__ __forceinline__ float h2f(unsigned short u) {
  return __half2float(__builtin_bit_cast(__half, u));
}

// branchless online LSE update (bit-identical to branchy form)
__device__ __forceinline__ void lse_add(float& mm, float& ss, float v) {
  float nm = fmaxf(mm, v);
  ss = fmaf(ss, __expf(mm - nm), __expf(v - nm));
  mm = nm;
}
__device__ __forceinline__ void lse_merge(float& mm, float& ss, float om, float os) {
  float nm = fmaxf(mm, om);
  ss = ss * __expf(mm - nm) + os * __expf(om - nm);
  mm = nm;
}

// global barrier, 64-block fan-in: epoch-payload slots (no reset needed),
// 64 release-stores to 64 slots; wave0 polls one slot per lane.
__device__ __forceinline__ void gbar(int* slots, int ep, int b, int t) {
  __syncthreads();
  if (t == 0) {
    __threadfence();
    __hip_atomic_store(&slots[b], ep, __ATOMIC_RELEASE, __HIP_MEMORY_SCOPE_AGENT);
  }
  if (t < SKB) {
    while (__hip_atomic_load(&slots[t], __ATOMIC_ACQUIRE,
                             __HIP_MEMORY_SCOPE_AGENT) < ep) {
      __builtin_amdgcn_s_sleep(1);
    }
  }
  __syncthreads();
  __threadfence();
}

// closed-form symmetric 3x3 eigenvalues (ascending), double precision
__device__ void eig3(double a00, double a01, double a02, double a11, double a12,
                     double a22, double* e) {
  double p1 = a01*a01 + a02*a02 + a12*a12;
  double q  = (a00 + a11 + a22) / 3.0;
  double b00 = a00 - q, b11 = a11 - q, b22 = a22 - q;
  double p2 = b00*b00 + b11*b11 + b22*b22 + 2.0*p1;
  if (p2 <= 1e-300) { e[0] = e[1] = e[2] = q; return; }
  double p = sqrt(p2 / 6.0);
  double ip = 1.0 / p;
  double c00 = b00*ip, c01 = a01*ip, c02 = a02*ip;
  double c11 = b11*ip, c12 = a12*ip, c22 = b22*ip;
  double detB = c00*(c11*c22 - c12*c12) - c01*(c01*c22 - c12*c02)
              + c02*(c01*c12 - c11*c02);
  double r = detB / 2.0;
  r = fmin(1.0, fmax(-1.0, r));
  double phi = acos(r) / 3.0;
  double e2 = q + 2.0*p*cos(phi);
  double e0 = q + 2.0*p*cos(phi + 2.0943951023931953);
  double e1 = 3.0*q - e2 - e0;
  e[0] = e0; e[1] = e1; e[2] = e2;
}

// ---------------- kernels ----------------

__global__ void k_init(unsigned long long* __restrict__ slots, int* __restrict__ bar1,
                       int* __restrict__ bar2) {
  int t = threadIdx.x;
  if (t < 3 * FNB) slots[t] = 0ULL;
  if (t < SKB) { bar1[t] = 0; bar2[t] = 0; }
}

// pack xyz + |x|^2 into float4
__global__ void k_prep(const float* __restrict__ xyz, float4* __restrict__ xyzs4) {
  int i = blockIdx.x * blockDim.x + threadIdx.x;
  if (i < NP) {
    float x = xyz[3*i+0], y = xyz[3*i+1], z = xyz[3*i+2];
    xyzs4[i] = make_float4(x, y, z, x*x + y*y + z*z);
  }
}

// FPS: 8 blocks x 1024 threads, 8 pts/thread in regs. Payload slot barrier,
// mod-3 phase buffering.
__global__ __launch_bounds__(1024) void k_fps3(const float4* __restrict__ xyzs4,
                                               int* __restrict__ cent,
                                               unsigned long long* __restrict__ slots) {
  const int t = threadIdx.x, b = blockIdx.x;
  const int base = (b * 1024 + t) * 8;
  float X[8], Y[8], Z[8], D[8];
#pragma unroll
  for (int k = 0; k < 8; ++k) {
    float4 p = xyzs4[base + k];
    X[k] = p.x; Y[k] = p.y; Z[k] = p.z; D[k] = 1e10f;
  }
  __shared__ unsigned long long swave[16];
  __shared__ unsigned long long swin;
  int cur = 0;
  float cx = xyzs4[0].x, cy = xyzs4[0].y, cz = xyzs4[0].z;
  const int lane = t & 63, wid = t >> 6;
  for (int it = 0; it < MP; ++it) {
    if (b == 0 && t == 0) cent[it] = cur;
    float bm = -1.0f; int bi = 0x7fffffff;
#pragma unroll
    for (int k = 0; k < 8; ++k) {
      float dx = X[k] - cx, dy = Y[k] - cy, dz = Z[k] - cz;
      float d = dx*dx + dy*dy + dz*dz;
      float nd = fminf(D[k], d);
      D[k] = nd;
      bool gt = (nd > bm);
      bi = gt ? (base + k) : bi;
      bm = gt ? nd : bm;
    }
    unsigned long long key =
        ((unsigned long long)__float_as_uint(bm) << 32) |
        (unsigned int)(0x7fffffff - bi);
#pragma unroll
    for (int off = 32; off > 0; off >>= 1) {
      unsigned long long o = __shfl_down(key, off);
      key = (o > key) ? o : key;
    }
    if (lane == 0) swave[wid] = key;
    __syncthreads();
    const int p = it % 3, pn = (it + 1) % 3;
    if (t == 0) {
      unsigned long long k0 = swave[0];
      for (int w = 1; w < 16; ++w) k0 = (swave[w] > k0) ? swave[w] : k0;
      __hip_atomic_store(&slots[pn * FNB + b], 0ULL, __ATOMIC_RELAXED,
                         __HIP_MEMORY_SCOPE_AGENT);
      __hip_atomic_store(&slots[p * FNB + b], k0, __ATOMIC_RELEASE,
                         __HIP_MEMORY_SCOPE_AGENT);
    }
    if (wid == 0) {
      unsigned long long v = 0ULL;
      if (lane < FNB) {
        do {
          v = __hip_atomic_load(&slots[p * FNB + lane], __ATOMIC_ACQUIRE,
                                __HIP_MEMORY_SCOPE_AGENT);
        } while (v == 0ULL);
      }
#pragma unroll
      for (int off = 32; off > 0; off >>= 1) {
        unsigned long long o = __shfl_down(v, off);
        v = (o > v) ? o : v;
      }
      if (lane == 0) swin = v;
    }
    __syncthreads();
    unsigned long long wkey = swin;
    cur = 0x7fffffff - (int)(wkey & 0xffffffffu);
    float4 cc = xyzs4[cur];
    cx = cc.x; cy = cc.y; cz = cc.z;
    __syncthreads();
  }
}

// gather proto xyz (+norm) and mean node
__global__ void k_gather1(const float* __restrict__ xyz, const int* __restrict__ cent,
                          float4* __restrict__ pxyzs4, float* __restrict__ meann) {
  __shared__ float sx[512], sy[512], sz[512];
  int m = threadIdx.x;
  int c = cent[m];
  float x = xyz[3*c+0], y = xyz[3*c+1], z = xyz[3*c+2];
  pxyzs4[m] = make_float4(x, y, z, x*x + y*y + z*z);
  sx[m] = x; sy[m] = y; sz[m] = z;
  __syncthreads();
  for (int off = 256; off > 0; off >>= 1) {
    if (m < off) { sx[m] += sx[m+off]; sy[m] += sy[m+off]; sz[m] += sz[m+off]; }
    __syncthreads();
  }
  if (m == 0) {
    meann[0] = sx[0] * (1.0f/512.0f);
    meann[1] = sy[0] * (1.0f/512.0f);
    meann[2] = sz[0] * (1.0f/512.0f);
  }
}

// gather proto features
__global__ void k_gatherf(const float* __restrict__ feats, const int* __restrict__ cent,
                          float* __restrict__ pf) {
  int m = blockIdx.x, c = threadIdx.x;
  pf[m*128 + c] = feats[(size_t)cent[m]*128 + c];
}

// ball query (first 10 smallest indices within radius) + PCA curvature -> dist_ge
__global__ void k_ballpca(const float4* __restrict__ xyzs4,
                          const float4* __restrict__ pxyzs4,
                          const float* __restrict__ meann,
                          float* __restrict__ ge) {
  const int m = blockIdx.x, t = threadIdx.x;
  __shared__ int lidx[256][NBALL];
  __shared__ int s_sel[NBALL];
  __shared__ int s_win;
  __shared__ int s_w4[4];
  float4 q = pxyzs4[m];
  int cnt = 0;
  for (int k = 0; k < 256; ++k) {
    int i = (k << 8) + t;
    float4 p = xyzs4[i];
    float dot = q.x*p.x + q.y*p.y + q.z*p.z;
    float d2 = (q.w + p.w) - 2.0f*dot;
    float d = sqrtf(fmaxf(d2, 0.0f));
    if (!(d > 0.04f) && cnt < NBALL) { lidx[t][cnt] = i; cnt++; }
  }
  __syncthreads();
  int hp = 0;
  for (int r = 0; r < NBALL; ++r) {
    int v = (hp < cnt) ? lidx[t][hp] : 0x7fffffff;
#pragma unroll
    for (int off = 32; off > 0; off >>= 1) v = min(v, __shfl_down(v, off));
    if ((t & 63) == 0) s_w4[t >> 6] = v;
    __syncthreads();
    if (t == 0) s_win = min(min(s_w4[0], s_w4[1]), min(s_w4[2], s_w4[3]));
    __syncthreads();
    int w = s_win;
    if (w != 0x7fffffff && hp < cnt && lidx[t][hp] == w) hp++;
    if (t == 0) s_sel[r] = w;
    __syncthreads();
  }
  if (t == 0) {
    float mx = meann[0], my = meann[1], mz = meann[2];
    int first = (s_sel[0] != 0x7fffffff) ? s_sel[0] : NP;
    float c00=0,c01=0,c02=0,c11=0,c12=0,c22=0;
    for (int r = 0; r < NBALL; ++r) {
      int id = s_sel[r];
      if (id == 0x7fffffff) id = first;
      float nx, ny, nz;
      if (id >= NP) { nx = mx; ny = my; nz = mz; }
      else { float4 p = xyzs4[id]; nx = p.x; ny = p.y; nz = p.z; }
      float dx = nx - q.x, dy = ny - q.y, dz = nz - q.z;
      c00 += dx*dx; c01 += dx*dy; c02 += dx*dz;
      c11 += dy*dy; c12 += dy*dz; c22 += dz*dz;
    }
    double e[3];
    eig3((double)(c00/10.0f + 1e-8f), (double)(c01/10.0f + 1e-8f),
         (double)(c02/10.0f + 1e-8f), (double)(c11/10.0f + 1e-8f),
         (double)(c12/10.0f + 1e-8f), (double)(c22/10.0f + 1e-8f), e);
    float l0 = (float)e[0], l1 = (float)e[1], l2r = (float)e[2];
    float l2 = fmaxf(l2r, 1e-8f);
    float f0 = (l2 - l1) / l2, f1 = (l1 - l0) / l2, f2 = l0 / l2;
    ge[m] = sqrtf(f0*f0 + f1*f1 + f2*f2) / sqrtf(3.0f);
  }
}

// fused sinkhorn 1: 64 blocks x 1024 threads persistent, 2 barriers/iter.
// row: 1 thread/row vs LDS protos; col: 8 whole cols/block (128 lanes each).
__global__ __launch_bounds__(1024) void k_sk1(const float4* __restrict__ xyzs4,
                                              const float4* __restrict__ pxyzs4,
                                              const float* __restrict__ ge,
                                              float* __restrict__ r,
                                              float* __restrict__ c,
                                              int* __restrict__ slots) {
  const int t = threadIdx.x, b = blockIdx.x;
  __shared__ float4 sp[MP];
  __shared__ float  su[MP];
  __shared__ float2 smrg2[8][2];
  int ep = 0;
  const int row = b * 1024 + t;
  const int jg = t >> 7, lanec = t & 127;
  const int jcol = b * 8 + jg;
  if (t < MP) sp[t] = pxyzs4[t];
  const float4 qv = xyzs4[row];
  const float4 pj = pxyzs4[jcol];
  const float g20 = ge[jcol] * NINV_TAU;
  __syncthreads();
  for (int it = 0; it < SKI; ++it) {
    if (t < MP) su[t] = fmaf(ge[t], NINV_TAU, it ? c[t] : 0.0f);
    __syncthreads();
    // ---- row pass: r_i = -LSE_j(K_ij + c_j) incl pad col ----
    float mm = 0.0f, ss = 1.0f;   // pad col contribution exp(0)
    for (int j = 0; j < MP; ++j) {
      float4 p = sp[j];
      float dot = qv.x*p.x + qv.y*p.y + qv.z*p.z;
      float dist = sqrtf(fmaxf((qv.w + p.w) - 2.0f*dot, 0.0f));
      lse_add(mm, ss, fmaf(dist, SCNT, su[j]));
    }
    r[row] = -(mm + __logf(ss));
    gbar(slots, ++ep, b, t);
    // ---- col pass: col jcol over all 64K pts, 128 lanes, 4-deep batch ----
    float m = -1e30f, s = 0.0f;
    for (int k0 = 0; k0 < 512; k0 += 4) {
      float4 pv[4]; float rv[4];
#pragma unroll
      for (int u = 0; u < 4; ++u) {
        int i = ((k0 + u) << 7) + lanec;
        pv[u] = xyzs4[i];
        rv[u] = r[i];
      }
#pragma unroll
      for (int u = 0; u < 4; ++u) {
        float dot = pv[u].x*pj.x + pv[u].y*pj.y + pv[u].z*pj.z;
        float dist = sqrtf(fmaxf((pv[u].w + pj.w) - 2.0f*dot, 0.0f));
        lse_add(m, s, fmaf(dist, SCNT, rv[u] + g20));
      }
    }
#pragma unroll
    for (int off = 32; off > 0; off >>= 1) {
      lse_merge(m, s, __shfl_down(m, off), __shfl_down(s, off));
    }
    if ((lanec & 63) == 0) smrg2[jg][lanec >> 6] = make_float2(m, s);
    __syncthreads();
    if (lanec == 0) {
      float2 o = smrg2[jg][1];
      lse_merge(m, s, o.x, o.y);
      lse_merge(m, s, 0.0f, 1.0f);  // pad row
      c[jcol] = -(m + __logf(s));
    }
    gbar(slots, ++ep, b, t);
  }
}

// partial gamma^T @ feats : grid (64 n-chunks, 8 m-tiles), 128 threads
__global__ void k_pfeat_part(const float4* __restrict__ xyzs4,
                             const float4* __restrict__ pxyzs4,
                             const float* __restrict__ ge, const float* __restrict__ c,
                             const float* __restrict__ r, const float* __restrict__ feats,
                             float* __restrict__ part) {
  const int t = threadIdx.x;
  const int nc = blockIdx.x;
  const int mt = blockIdx.y;
  __shared__ float4 spp[64];
  __shared__ float  ssu[64];
  __shared__ float  sf[64][128];
  __shared__ float  sw[64][64];
  __shared__ float  srr[64];
  if (t < 64) {
    int j = mt*64 + t;
    spp[t] = pxyzs4[j];
    ssu[t] = fmaf(ge[j], NINV_TAU, c[j]);
  }
  const int mg = t >> 4;
  const int cg = t & 15;
  float acc[8][8];
#pragma unroll
  for (int a = 0; a < 8; ++a)
#pragma unroll
    for (int b = 0; b < 8; ++b) acc[a][b] = 0.0f;
  for (int bt = 0; bt < 16; ++bt) {
    int n0 = nc*1024 + bt*64;
    __syncthreads();
    for (int q2 = t; q2 < 2048; q2 += 128) {
      int row = q2 >> 5, c4 = q2 & 31;
      ((float4*)&sf[row][0])[c4] = ((const float4*)feats)[(size_t)(n0+row)*32 + c4];
    }
    if (t < 64) srr[t] = r[n0 + t];
    __syncthreads();
    for (int q2 = t; q2 < 4096; q2 += 128) {
      int nl = q2 >> 6, ml = q2 & 63;
      float4 qv = xyzs4[n0 + nl];
      float4 p = spp[ml];
      float dot = qv.x*p.x + qv.y*p.y + qv.z*p.z;
      float dist = sqrtf(fmaxf((qv.w + p.w) - 2.0f*dot, 0.0f));
      sw[nl][ml] = __expf(fmaf(dist, SCNT, ssu[ml] + srr[nl]));
    }
    __syncthreads();
#pragma unroll 8
    for (int n = 0; n < 64; ++n) {
      float4 w0 = ((float4*)&sw[n][0])[mg*2];
      float4 w1 = ((float4*)&sw[n][0])[mg*2+1];
      float4 f0 = ((float4*)&sf[n][0])[cg*2];
      float4 f1 = ((float4*)&sf[n][0])[cg*2+1];
      float wv[8] = {w0.x,w0.y,w0.z,w0.w,w1.x,w1.y,w1.z,w1.w};
      float fv[8] = {f0.x,f0.y,f0.z,f0.w,f1.x,f1.y,f1.z,f1.w};
#pragma unroll
      for (int a = 0; a < 8; ++a)
#pragma unroll
        for (int b = 0; b < 8; ++b) acc[a][b] = fmaf(wv[a], fv[b], acc[a][b]);
    }
  }
  for (int a = 0; a < 8; ++a) {
    int m = mt*64 + mg*8 + a;
    float* dst = &part[((size_t)nc*MP + m)*128 + cg*8];
    ((float4*)dst)[0] = make_float4(acc[a][0], acc[a][1], acc[a][2], acc[a][3]);
    ((float4*)dst)[1] = make_float4(acc[a][4], acc[a][5], acc[a][6], acc[a][7]);
  }
}

__global__ void k_pfeat_red(const float* __restrict__ part, const float* __restrict__ pf,
                            float* __restrict__ p1) {
  int idx = blockIdx.x*256 + threadIdx.x;
  float s = 0.0f;
  for (int ncb = 0; ncb < 64; ++ncb) s += part[(size_t)ncb*MP*128 + idx];
  p1[idx] = 0.5f*pf[idx] + 0.5f*s;
}

// sim column + top-20 aggregation -> p2
__global__ void k_simtopk(const float* __restrict__ p1, float* __restrict__ p2) {
  const int m = blockIdx.x, t = threadIdx.x;
  __shared__ float spm[128];
  __shared__ float scol[MP];
  __shared__ float sval[20];
  __shared__ int   sid[20];
  __shared__ float sredv[2];
  __shared__ int   sredi[2];
  __shared__ float sden;
  spm[t] = p1[m*128 + t];
  __syncthreads();
  for (int kk = t; kk < MP; kk += 128) {
    float a = 0.0f;
    const float* row = &p1[kk*128];
#pragma unroll 8
    for (int c2 = 0; c2 < 128; ++c2) a = fmaf(row[c2], spm[c2], a);
    scol[kk] = a * SCF;
  }
  __syncthreads();
  for (int rs = 0; rs < 20; ++rs) {
    float bv = -1e30f; int bI = 1 << 30;
    for (int kk = t; kk < MP; kk += 128) {
      float v = scol[kk];
      if (v > bv) { bv = v; bI = kk; }
    }
#pragma unroll
    for (int off = 32; off > 0; off >>= 1) {
      float ov = __shfl_down(bv, off); int oi = __shfl_down(bI, off);
      if (ov > bv || (ov == bv && oi < bI)) { bv = ov; bI = oi; }
    }
    if ((t & 63) == 0) { sredv[t>>6] = bv; sredi[t>>6] = bI; }
    __syncthreads();
    if (t == 0) {
      float v1 = sredv[1]; int i1 = sredi[1];
      if (v1 > bv || (v1 == bv && i1 < bI)) { bv = v1; bI = i1; }
      sval[rs] = bv; sid[rs] = bI;
      scol[bI] = -1e30f;
    }
    __syncthreads();
  }
  if (t == 0) {
    float s = 0.0f;
    for (int rs = 0; rs < 20; ++rs) s += sval[rs];
    sden = fmaxf(s, 1e-4f);
  }
  __syncthreads();
  float a = 0.0f;
  float den = sden;
  for (int rs = 0; rs < 20; ++rs) {
    float w = sval[rs] / den;
    a = fmaf(w, p1[sid[rs]*128 + t], a);
  }
  p2[m*128 + t] = 0.5f*p1[m*128 + t] + 0.5f*a;
}

// sim_pt = feats @ p2^T * sc (stored fp16) : grid (1024, 8), block 256
__global__ void k_simpt(const float* __restrict__ feats, const float* __restrict__ p2,
                        __half* __restrict__ sim) {
  const int t = threadIdx.x;
  const int nt = blockIdx.x;
  const int mt = blockIdx.y;
  __shared__ float sa[64][68];
  __shared__ float sb[64][68];
  const int tn = t >> 4, tm = t & 15;
  float acc[4][4];
#pragma unroll
  for (int x = 0; x < 4; ++x)
#pragma unroll
    for (int y = 0; y < 4; ++y) acc[x][y] = 0.0f;
  for (int kh = 0; kh < 2; ++kh) {
    __syncthreads();
    for (int q2 = t; q2 < 1024; q2 += 256) {
      int row = q2 >> 4, c4 = q2 & 15;
      ((float4*)&sa[row][0])[c4] =
          ((const float4*)feats)[(size_t)(nt*64+row)*32 + kh*16 + c4];
      ((float4*)&sb[row][0])[c4] =
          ((const float4*)p2)[(size_t)(mt*64+row)*32 + kh*16 + c4];
    }
    __syncthreads();
    for (int k = 0; k < 64; ++k) {
      float av[4], bv[4];
#pragma unroll
      for (int x = 0; x < 4; ++x) av[x] = sa[tn*4+x][k];
#pragma unroll
      for (int y = 0; y < 4; ++y) bv[y] = sb[tm*4+y][k];
#pragma unroll
      for (int x = 0; x < 4; ++x)
#pragma unroll
        for (int y = 0; y < 4; ++y) acc[x][y] = fmaf(av[x], bv[y], acc[x][y]);
    }
  }
  for (int x = 0; x < 4; ++x)
    for (int y = 0; y < 4; ++y) {
      int n = nt*64 + tn*4 + x, mc = mt*64 + tm*4 + y;
      sim[(size_t)n*MP + mc] = __float2half(acc[x][y] * SCF);
    }
}

// fused sinkhorn 2 over fp16 sim: 64 blocks x 1024 threads, 3 barriers/iter.
// row: 1 thread/row; col-partial: block's contiguous 1024-row slab; reduce: 8 cols/block.
__global__ __launch_bounds__(1024) void k_sk2(const __half* __restrict__ sim,
                                              float* __restrict__ r,
                                              float* __restrict__ c,
                                              float2* __restrict__ part,
                                              int* __restrict__ slots) {
  const int t = threadIdx.x, b = blockIdx.x;
  __shared__ float scc[MP];
  __shared__ float sr[1024];
  __shared__ float2 smrg[512];
  int ep = 0;
  const int row = b * 1024 + t;
  const us8* v8 = (const us8*)(sim + (size_t)row * MP);
  const int ct = t & 511, rh = t >> 9;
  for (int it = 0; it < SKI; ++it) {
    if (t < MP) scc[t] = it ? c[t] : 0.0f;
    __syncthreads();
    // ---- row pass: full 512 cols per thread, 8-deep batched us8 loads ----
    float mm = 0.0f, ss = 1.0f;   // pad col
    for (int g0 = 0; g0 < 64; g0 += 8) {
      us8 u[8];
#pragma unroll
      for (int g = 0; g < 8; ++g) u[g] = v8[g0 + g];
#pragma unroll
      for (int g = 0; g < 8; ++g)
#pragma unroll
        for (int e = 0; e < 8; ++e) {
          lse_add(mm, ss, fmaf(h2f(u[g][e]), NINV_TAU, scc[(g0+g)*8 + e]));
        }
    }
    r[row] = -(mm + __logf(ss));
    gbar(slots, ++ep, b, t);
    // ---- col partial: rows [b*1024 + rh*512, +512) for col ct ----
    sr[t] = r[b * 1024 + t];
    __syncthreads();
    float m = -1e30f, s = 0.0f;
    const int r0 = rh * 512;
    for (int k0 = 0; k0 < 512; k0 += 8) {
      float v[8];
#pragma unroll
      for (int u2 = 0; u2 < 8; ++u2)
        v[u2] = __half2float(sim[(size_t)(b*1024 + r0 + k0 + u2) * MP + ct]);
#pragma unroll
      for (int u2 = 0; u2 < 8; ++u2)
        lse_add(m, s, fmaf(v[u2], NINV_TAU, sr[r0 + k0 + u2]));
    }
    if (rh == 1) smrg[ct] = make_float2(m, s);
    __syncthreads();
    if (rh == 0) {
      float2 o = smrg[ct];
      lse_merge(m, s, o.x, o.y);
      part[(size_t)b * MP + ct] = make_float2(m, s);
    }
    gbar(slots, ++ep, b, t);
    // ---- reduce 64 partials per col; 8 cols/block (threads < 512) ----
    if (t < 512) {
      const int col = b * 8 + (t >> 6), lane = t & 63;
      float2 pv = part[(size_t)lane * MP + col];
      float M = pv.x, S = pv.y;
#pragma unroll
      for (int off = 32; off > 0; off >>= 1) {
        lse_merge(M, S, __shfl_down(M, off), __shfl_down(S, off));
      }
      if (lane == 0) {
        lse_merge(M, S, 0.0f, 1.0f);  // pad row
        c[col] = -(M + __logf(S));
      }
    }
    gbar(slots, ++ep, b, t);
  }
}

// refined = 0.5*feats + 0.5 * w @ p2  (w = exp(K + r + c) recomputed)
__global__ void k_refined(const __half* __restrict__ sim, const float* __restrict__ r,
                          const float* __restrict__ c, const float* __restrict__ p2,
                          const float* __restrict__ feats, float* __restrict__ out) {
  const int t = threadIdx.x;
  const int nb = blockIdx.x;  // 64 rows per block
  __shared__ float sp[64][128];
  __shared__ float sw[64][68];
  __shared__ float srr[64], scc[64];
  const int tn = t >> 5, tc = t & 31;
  if (t < 64) srr[t] = r[nb*64 + t];
  float acc[8][4];
#pragma unroll
  for (int a = 0; a < 8; ++a)
#pragma unroll
    for (int b = 0; b < 4; ++b) acc[a][b] = 0.0f;
  for (int mt2 = 0; mt2 < 8; ++mt2) {
    __syncthreads();
    for (int q2 = t; q2 < 2048; q2 += 256) {
      int row = q2 >> 5, c4 = q2 & 31;
      ((float4*)&sp[row][0])[c4] = ((const float4*)p2)[(size_t)(mt2*64+row)*32 + c4];
    }
    if (t < 64) scc[t] = c[mt2*64 + t];
    __syncthreads();
    for (int q2 = t; q2 < 4096; q2 += 256) {
      int nl = q2 >> 6, ml = q2 & 63;
      float val = __half2float(sim[(size_t)(nb*64+nl)*MP + mt2*64 + ml]);
      sw[nl][ml] = __expf(fmaf(val, NINV_TAU, srr[nl] + scc[ml]));
    }
    __syncthreads();
    for (int mm2 = 0; mm2 < 64; ++mm2) {
      float4 pv = ((float4*)&sp[mm2][0])[tc];
      float wv[8];
#pragma unroll
      for (int a = 0; a < 8; ++a) wv[a] = sw[tn*8+a][mm2];
#pragma unroll
      for (int a = 0; a < 8; ++a) {
        acc[a][0] = fmaf(wv[a], pv.x, acc[a][0]);
        acc[a][1] = fmaf(wv[a], pv.y, acc[a][1]);
        acc[a][2] = fmaf(wv[a], pv.z, acc[a][2]);
        acc[a][3] = fmaf(wv[a], pv.w, acc[a][3]);
      }
    }
  }
  for (int a = 0; a < 8; ++a) {
    int row = nb*64 + tn*8 + a;
    float4 f = ((const float4*)feats)[(size_t)row*32 + tc];
    float4 o;
    o.x = 0.5f*f.x + 0.5f*acc[a][0];
    o.y = 0.5f*f.y + 0.5f*acc[a][1];
    o.z = 0.5f*f.z + 0.5f*acc[a][2];
    o.w = 0.5f*f.w + 0.5f*acc[a][3];
    ((float4*)out)[(size_t)row*32 + tc] = o;
  }
}

// ---------------- launcher ----------------

extern "C" void kernel_launch(void* const* d_in, const int* in_sizes, int n_in,
                              void* d_out, int out_size, void* d_ws, size_t ws_size,
                              hipStream_t stream) {
  (void)in_sizes; (void)n_in; (void)out_size; (void)ws_size;
  const float* xyz   = (const float*)d_in[0];
  const float* feats = (const float*)d_in[1];
  float* out = (float*)d_out;
  char* ws = (char*)d_ws;

  auto al = [](size_t x) { return (x + 255) & ~(size_t)255; };
  // sim (fp16, 64MB) overlaps partA (float, 16.8MB): partA consumed before sim written
  __half* sim  = (__half*)ws;
  float* partA = (float*)ws;
  size_t o = al((size_t)NP * MP * 2);
  float4* xyzs4 = (float4*)(ws + o); o += al((size_t)NP * 16);
  float* rbuf   = (float*)(ws + o);  o += al((size_t)NP * 4);
  float* cbuf   = (float*)(ws + o);  o += al((size_t)MP * 4);
  int*   cent   = (int*)(ws + o);    o += al((size_t)MP * 4);
  float4* pxyzs4 = (float4*)(ws + o); o += al((size_t)MP * 16);
  float* ge     = (float*)(ws + o);  o += al((size_t)MP * 4);
  float* meann  = (float*)(ws + o);  o += al((size_t)256);
  float* pf     = (float*)(ws + o);  o += al((size_t)MP * 128 * 4);
  float* p1     = (float*)(ws + o);  o += al((size_t)MP * 128 * 4);
  float* p2     = (float*)(ws + o);  o += al((size_t)MP * 128 * 4);
  float2* part2 = (float2*)(ws + o); o += al((size_t)SKB * MP * 8);
  unsigned long long* fslots = (unsigned long long*)(ws + o);
  o += al((size_t)3 * FNB * 8);
  int* bar1 = (int*)(ws + o); o += al((size_t)256);
  int* bar2 = (int*)(ws + o); o += al((size_t)256);

  k_init<<<dim3(1), dim3(256), 0, stream>>>(fslots, bar1, bar2);
  k_prep<<<dim3(256), dim3(256), 0, stream>>>(xyz, xyzs4);
  k_fps3<<<dim3(FNB), dim3(1024), 0, stream>>>(xyzs4, cent, fslots);
  k_gather1<<<dim3(1), dim3(512), 0, stream>>>(xyz, cent, pxyzs4, meann);
  k_gatherf<<<dim3(512), dim3(128), 0, stream>>>(feats, cent, pf);
  k_ballpca<<<dim3(512), dim3(256), 0, stream>>>(xyzs4, pxyzs4, meann, ge);

  k_sk1<<<dim3(SKB), dim3(1024), 0, stream>>>(xyzs4, pxyzs4, ge, rbuf, cbuf, bar1);

  k_pfeat_part<<<dim3(64, 8), dim3(128), 0, stream>>>(xyzs4, pxyzs4, ge, cbuf, rbuf,
                                                      feats, partA);
  k_pfeat_red<<<dim3(256), dim3(256), 0, stream>>>(partA, pf, p1);
  k_simtopk<<<dim3(512), dim3(128), 0, stream>>>(p1, p2);

  k_simpt<<<dim3(1024, 8), dim3(256), 0, stream>>>(feats, p2, sim);
  k_sk2<<<dim3(SKB), dim3(1024), 0, stream>>>(sim, rbuf, cbuf, part2, bar2);
  k_refined<<<dim3(1024), dim3(256), 0, stream>>>(sim, rbuf, cbuf, p2, feats, out);
}

// Round 7
// 5000.029 us; speedup vs baseline: 2.4135x; 2.1758x over previous
//
#include <hip/hip_runtime.h>
#include <hip/hip_fp16.h>
#include <math.h>

#define NP 65536
#define MP 512
#define SKI 20
#define NBALL 10

#define FNB 32      // fps blocks
#define SKB2 64     // sinkhorn blocks

// f32(-1/0.05f) rounds exactly to -20.0f
#define NINV_TAU (-20.0f)
// 1/f32(sqrt(128)) ; sc = 1/sqrt(C)
#define SCF (1.0f / 11.313708305358886719f)
#define SCNT (SCF * NINV_TAU)

typedef unsigned short us8 __attribute__((ext_vector_type(8)));

// ---------------- helpers ----------------

__device__ __forceinline__ float h2f(unsigned short u) {
  return __half2float(__builtin_bit_cast(__half, u));
}
__device__ __forceinline__ unsigned short f2h(float f) {
  return __builtin_bit_cast(unsigned short, __float2half(f));
}

// agent-scope atomic f32 publish/read (bypass incoherent L1/L2; no fences)
__device__ __forceinline__ void pub_f32(float* p, float v) {
  __hip_atomic_store((unsigned int*)p, __float_as_uint(v), __ATOMIC_RELAXED,
                     __HIP_MEMORY_SCOPE_AGENT);
}
__device__ __forceinline__ float rd_f32(const float* p) {
  return __uint_as_float(__hip_atomic_load((const unsigned int*)p,
                                           __ATOMIC_RELAXED,
                                           __HIP_MEMORY_SCOPE_AGENT));
}

// fps-style fence-free barrier: release epoch store + acquire poll. 64 fan-in.
__device__ __forceinline__ void gbar(int* slots, int ep, int b, int t) {
  __syncthreads();
  if (t == 0) {
    __hip_atomic_store(&slots[b], ep, __ATOMIC_RELEASE, __HIP_MEMORY_SCOPE_AGENT);
  }
  if (t < SKB2) {
    while (__hip_atomic_load(&slots[t], __ATOMIC_ACQUIRE,
                             __HIP_MEMORY_SCOPE_AGENT) < ep) {}
  }
  __syncthreads();
}

// closed-form symmetric 3x3 eigenvalues (ascending), double precision
__device__ void eig3(double a00, double a01, double a02, double a11, double a12,
                     double a22, double* e) {
  double p1 = a01*a01 + a02*a02 + a12*a12;
  double q  = (a00 + a11 + a22) / 3.0;
  double b00 = a00 - q, b11 = a11 - q, b22 = a22 - q;
  double p2 = b00*b00 + b11*b11 + b22*b22 + 2.0*p1;
  if (p2 <= 1e-300) { e[0] = e[1] = e[2] = q; return; }
  double p = sqrt(p2 / 6.0);
  double ip = 1.0 / p;
  double c00 = b00*ip, c01 = a01*ip, c02 = a02*ip;
  double c11 = b11*ip, c12 = a12*ip, c22 = b22*ip;
  double detB = c00*(c11*c22 - c12*c12) - c01*(c01*c22 - c12*c02)
              + c02*(c01*c12 - c11*c02);
  double r = detB / 2.0;
  r = fmin(1.0, fmax(-1.0, r));
  double phi = acos(r) / 3.0;
  double e2 = q + 2.0*p*cos(phi);
  double e0 = q + 2.0*p*cos(phi + 2.0943951023931953);
  double e1 = 3.0*q - e2 - e0;
  e[0] = e0; e[1] = e1; e[2] = e2;
}

// ---------------- kernels ----------------

__global__ void k_init(unsigned long long* __restrict__ slots, int* __restrict__ bar1,
                       int* __restrict__ bar2) {
  int t = threadIdx.x;
  if (t < 3 * FNB) slots[t] = 0ULL;
  if (t < SKB2) { bar1[t] = 0; bar2[t] = 0; }
}

// pack xyz + |x|^2 into float4
__global__ void k_prep(const float* __restrict__ xyz, float4* __restrict__ xyzs4) {
  int i = blockIdx.x * blockDim.x + threadIdx.x;
  if (i < NP) {
    float x = xyz[3*i+0], y = xyz[3*i+1], z = xyz[3*i+2];
    xyzs4[i] = make_float4(x, y, z, x*x + y*y + z*z);
  }
}

// FPS: 32 blocks x 256 threads, 8 pts/thread in regs (R3-proven config).
__global__ __launch_bounds__(256) void k_fps3(const float4* __restrict__ xyzs4,
                                              int* __restrict__ cent,
                                              unsigned long long* __restrict__ slots) {
  const int t = threadIdx.x, b = blockIdx.x;
  const int base = (b * 256 + t) * 8;
  float X[8], Y[8], Z[8], D[8];
#pragma unroll
  for (int k = 0; k < 8; ++k) {
    float4 p = xyzs4[base + k];
    X[k] = p.x; Y[k] = p.y; Z[k] = p.z; D[k] = 1e10f;
  }
  __shared__ unsigned long long swave[4];
  __shared__ unsigned long long swin;
  int cur = 0;
  float cx = xyzs4[0].x, cy = xyzs4[0].y, cz = xyzs4[0].z;
  const int lane = t & 63, wid = t >> 6;
  for (int it = 0; it < MP; ++it) {
    if (b == 0 && t == 0) cent[it] = cur;
    float bm = -1.0f; int bi = 0x7fffffff;
#pragma unroll
    for (int k = 0; k < 8; ++k) {
      float dx = X[k] - cx, dy = Y[k] - cy, dz = Z[k] - cz;
      float d = dx*dx + dy*dy + dz*dz;
      float nd = fminf(D[k], d);
      D[k] = nd;
      bool gt = (nd > bm);
      bi = gt ? (base + k) : bi;
      bm = gt ? nd : bm;
    }
    unsigned long long key =
        ((unsigned long long)__float_as_uint(bm) << 32) |
        (unsigned int)(0x7fffffff - bi);
#pragma unroll
    for (int off = 32; off > 0; off >>= 1) {
      unsigned long long o = __shfl_down(key, off);
      key = (o > key) ? o : key;
    }
    if (lane == 0) swave[wid] = key;
    __syncthreads();
    const int p = it % 3, pn = (it + 1) % 3;
    if (t == 0) {
      unsigned long long k0 = swave[0];
      for (int w = 1; w < 4; ++w) k0 = (swave[w] > k0) ? swave[w] : k0;
      __hip_atomic_store(&slots[pn * FNB + b], 0ULL, __ATOMIC_RELAXED,
                         __HIP_MEMORY_SCOPE_AGENT);
      __hip_atomic_store(&slots[p * FNB + b], k0, __ATOMIC_RELEASE,
                         __HIP_MEMORY_SCOPE_AGENT);
    }
    if (wid == 0) {
      unsigned long long v = 0ULL;
      if (lane < FNB) {
        do {
          v = __hip_atomic_load(&slots[p * FNB + lane], __ATOMIC_ACQUIRE,
                                __HIP_MEMORY_SCOPE_AGENT);
        } while (v == 0ULL);
      }
#pragma unroll
      for (int off = 32; off > 0; off >>= 1) {
        unsigned long long o = __shfl_down(v, off);
        v = (o > v) ? o : v;
      }
      if (lane == 0) swin = v;
    }
    __syncthreads();
    unsigned long long wkey = swin;
    cur = 0x7fffffff - (int)(wkey & 0xffffffffu);
    float4 cc = xyzs4[cur];
    cx = cc.x; cy = cc.y; cz = cc.z;
    __syncthreads();
  }
}

// gather proto xyz (+norm) and mean node
__global__ void k_gather1(const float* __restrict__ xyz, const int* __restrict__ cent,
                          float4* __restrict__ pxyzs4, float* __restrict__ meann) {
  __shared__ float sx[512], sy[512], sz[512];
  int m = threadIdx.x;
  int c = cent[m];
  float x = xyz[3*c+0], y = xyz[3*c+1], z = xyz[3*c+2];
  pxyzs4[m] = make_float4(x, y, z, x*x + y*y + z*z);
  sx[m] = x; sy[m] = y; sz[m] = z;
  __syncthreads();
  for (int off = 256; off > 0; off >>= 1) {
    if (m < off) { sx[m] += sx[m+off]; sy[m] += sy[m+off]; sz[m] += sz[m+off]; }
    __syncthreads();
  }
  if (m == 0) {
    meann[0] = sx[0] * (1.0f/512.0f);
    meann[1] = sy[0] * (1.0f/512.0f);
    meann[2] = sz[0] * (1.0f/512.0f);
  }
}

// gather proto features
__global__ void k_gatherf(const float* __restrict__ feats, const int* __restrict__ cent,
                          float* __restrict__ pf) {
  int m = blockIdx.x, c = threadIdx.x;
  pf[m*128 + c] = feats[(size_t)cent[m]*128 + c];
}

// ball query (first 10 smallest indices within radius) + PCA curvature -> dist_ge
__global__ void k_ballpca(const float4* __restrict__ xyzs4,
                          const float4* __restrict__ pxyzs4,
                          const float* __restrict__ meann,
                          float* __restrict__ ge) {
  const int m = blockIdx.x, t = threadIdx.x;
  __shared__ int lidx[256][NBALL];
  __shared__ int s_sel[NBALL];
  __shared__ int s_win;
  __shared__ int s_w4[4];
  float4 q = pxyzs4[m];
  int cnt = 0;
  for (int k = 0; k < 256; ++k) {
    int i = (k << 8) + t;
    float4 p = xyzs4[i];
    float dot = q.x*p.x + q.y*p.y + q.z*p.z;
    float d2 = (q.w + p.w) - 2.0f*dot;
    float d = sqrtf(fmaxf(d2, 0.0f));
    if (!(d > 0.04f) && cnt < NBALL) { lidx[t][cnt] = i; cnt++; }
  }
  __syncthreads();
  int hp = 0;
  for (int r = 0; r < NBALL; ++r) {
    int v = (hp < cnt) ? lidx[t][hp] : 0x7fffffff;
#pragma unroll
    for (int off = 32; off > 0; off >>= 1) v = min(v, __shfl_down(v, off));
    if ((t & 63) == 0) s_w4[t >> 6] = v;
    __syncthreads();
    if (t == 0) s_win = min(min(s_w4[0], s_w4[1]), min(s_w4[2], s_w4[3]));
    __syncthreads();
    int w = s_win;
    if (w != 0x7fffffff && hp < cnt && lidx[t][hp] == w) hp++;
    if (t == 0) s_sel[r] = w;
    __syncthreads();
  }
  if (t == 0) {
    float mx = meann[0], my = meann[1], mz = meann[2];
    int first = (s_sel[0] != 0x7fffffff) ? s_sel[0] : NP;
    float c00=0,c01=0,c02=0,c11=0,c12=0,c22=0;
    for (int r = 0; r < NBALL; ++r) {
      int id = s_sel[r];
      if (id == 0x7fffffff) id = first;
      float nx, ny, nz;
      if (id >= NP) { nx = mx; ny = my; nz = mz; }
      else { float4 p = xyzs4[id]; nx = p.x; ny = p.y; nz = p.z; }
      float dx = nx - q.x, dy = ny - q.y, dz = nz - q.z;
      c00 += dx*dx; c01 += dx*dy; c02 += dx*dz;
      c11 += dy*dy; c12 += dy*dz; c22 += dz*dz;
    }
    double e[3];
    eig3((double)(c00/10.0f + 1e-8f), (double)(c01/10.0f + 1e-8f),
         (double)(c02/10.0f + 1e-8f), (double)(c11/10.0f + 1e-8f),
         (double)(c12/10.0f + 1e-8f), (double)(c22/10.0f + 1e-8f), e);
    float l0 = (float)e[0], l1 = (float)e[1], l2r = (float)e[2];
    float l2 = fmaxf(l2r, 1e-8f);
    float f0 = (l2 - l1) / l2, f1 = (l1 - l0) / l2, f2 = l0 / l2;
    ge[m] = sqrtf(f0*f0 + f1*f1 + f2*f2) / sqrtf(3.0f);
  }
}

// E1 = fp16(exp(dist(i,j) * SCNT)); 512 blocks x 256 thr; 2 thr/row, 256 cols each
__global__ void k_e1(const float4* __restrict__ xyzs4,
                     const float4* __restrict__ pxyzs4,
                     unsigned short* __restrict__ E1) {
  const int t = threadIdx.x, b = blockIdx.x;
  __shared__ float4 spp[MP];
  spp[t] = pxyzs4[t];
  spp[t + 256] = pxyzs4[t + 256];
  __syncthreads();
  const int row = b * 128 + (t >> 1);
  const int h = t & 1;
  const float4 q = xyzs4[row];
  us8* dst = (us8*)(E1 + (size_t)row * MP + h * 256);
  for (int g = 0; g < 32; ++g) {
    us8 v;
#pragma unroll
    for (int e = 0; e < 8; ++e) {
      float4 p = spp[h*256 + g*8 + e];
      float dot = q.x*p.x + q.y*p.y + q.z*p.z;
      float dist = sqrtf(fmaxf((q.w + p.w) - 2.0f*dot, 0.0f));
      v[e] = f2h(__expf(dist * SCNT));
    }
    dst[g] = v;
  }
}

// in-place transform: sim(fp16) -> E2 = fp16(exp(sim*NT - B_row)); ebn = exp(-B)
__global__ void k_e2(unsigned short* __restrict__ sim, float* __restrict__ ebn) {
  const int row = blockIdx.x * blockDim.x + threadIdx.x;
  us8* v8 = (us8*)(sim + (size_t)row * MP);
  float B = -1e30f;
  for (int g = 0; g < 64; ++g) {
    us8 u = v8[g];
#pragma unroll
    for (int e = 0; e < 8; ++e) B = fmaxf(B, h2f(u[e]) * NINV_TAU);
  }
  ebn[row] = __expf(-B);
  for (int g = 0; g < 64; ++g) {
    us8 u = v8[g];
    us8 w;
#pragma unroll
    for (int e = 0; e < 8; ++e) w[e] = f2h(__expf(h2f(u[e]) * NINV_TAU - B));
    v8[g] = w;
  }
}

// fused factorized sinkhorn 1: 64 blocks x 1024 thr, 1 fence-free barrier/iter.
// E1 in fp16; V_i = 1 + sum_j E1*G_j*C_j; Rr=1/V; col partials block-local.
__global__ __launch_bounds__(1024) void k_sk1(const unsigned short* __restrict__ E1,
                                              const float* __restrict__ ge,
                                              float* __restrict__ rr_out,
                                              float* __restrict__ gc_out,
                                              float* __restrict__ partbuf,
                                              int* __restrict__ slots) {
  const int t = threadIdx.x, b = blockIdx.x;
  __shared__ float sG[MP];
  __shared__ float sGC[MP];
  __shared__ float sRr[1024];
  __shared__ float scol[MP];
  if (t < MP) {
    float g = __expf(ge[t] * NINV_TAU);
    sG[t] = g;
    sGC[t] = g;   // C^0 = 1
  }
  __syncthreads();
  const int row = b * 1024 + t;
  const us8* e8 = (const us8*)(E1 + (size_t)row * MP);
  const int ct = t & 511, rh = t >> 9;
  for (int it = 0; it < SKI; ++it) {
    // ---- row: V = 1 + sum_j E1_ij * (G_j C_j) ----
    float V = 1.0f;
    for (int g0 = 0; g0 < 64; g0 += 8) {
      us8 u[8];
#pragma unroll
      for (int g = 0; g < 8; ++g) u[g] = e8[g0 + g];
#pragma unroll
      for (int g = 0; g < 8; ++g)
#pragma unroll
        for (int e = 0; e < 8; ++e)
          V = fmaf(h2f(u[g][e]), sGC[(g0+g)*8 + e], V);
    }
    float Rr = 1.0f / V;
    sRr[t] = Rr;
    __syncthreads();
    // ---- col partial over slab: S_j = sum_i E1_ij * Rr_i ----
    float S = 0.0f;
    const int r0 = rh * 512;
    for (int k0 = 0; k0 < 512; k0 += 8) {
      float v[8];
#pragma unroll
      for (int u2 = 0; u2 < 8; ++u2)
        v[u2] = h2f(E1[(size_t)(b*1024 + r0 + k0 + u2) * MP + ct]);
#pragma unroll
      for (int u2 = 0; u2 < 8; ++u2)
        S = fmaf(v[u2], sRr[r0 + k0 + u2], S);
    }
    if (rh == 1) scol[ct] = S;
    __syncthreads();
    if (rh == 0) {
      S += scol[ct];
      pub_f32(&partbuf[((it & 1) << 15) + (ct << 6) + b], S);
    }
    gbar(slots, it + 1, b, t);
    // ---- reduce + new C (redundant per block) ----
    if (t < MP) {
      const float* pb = &partbuf[((it & 1) << 15) + (t << 6)];
      float Sm = 0.0f;
      for (int q = 0; q < SKB2; ++q) Sm += rd_f32(&pb[q]);
      float Cj = 1.0f / fmaf(sG[t], Sm, 1.0f);
      sGC[t] = sG[t] * Cj;
    }
    __syncthreads();
  }
  rr_out[row] = sRr[t];
  if (b == 0 && t < MP) gc_out[t] = sGC[t];
}

// partial gamma^T @ feats using E1: gamma = E1 * gc_j * rr_i
__global__ void k_pfeat_part(const unsigned short* __restrict__ E1,
                             const float* __restrict__ gc, const float* __restrict__ rr,
                             const float* __restrict__ feats,
                             float* __restrict__ part) {
  const int t = threadIdx.x;
  const int nc = blockIdx.x;
  const int mt = blockIdx.y;
  __shared__ float sgc[64];
  __shared__ float sf[64][128];
  __shared__ float sw[64][64];
  __shared__ float srr[64];
  if (t < 64) sgc[t] = gc[mt*64 + t];
  const int mg = t >> 4;
  const int cg = t & 15;
  float acc[8][8];
#pragma unroll
  for (int a = 0; a < 8; ++a)
#pragma unroll
    for (int b2 = 0; b2 < 8; ++b2) acc[a][b2] = 0.0f;
  for (int bt = 0; bt < 16; ++bt) {
    int n0 = nc*1024 + bt*64;
    __syncthreads();
    for (int q2 = t; q2 < 2048; q2 += 128) {
      int row = q2 >> 5, c4 = q2 & 31;
      ((float4*)&sf[row][0])[c4] = ((const float4*)feats)[(size_t)(n0+row)*32 + c4];
    }
    if (t < 64) srr[t] = rr[n0 + t];
    __syncthreads();
    for (int q2 = t; q2 < 4096; q2 += 128) {
      int nl = q2 >> 6, ml = q2 & 63;
      float ev = h2f(E1[(size_t)(n0+nl)*MP + mt*64 + ml]);
      sw[nl][ml] = ev * sgc[ml] * srr[nl];
    }
    __syncthreads();
#pragma unroll 8
    for (int n = 0; n < 64; ++n) {
      float4 w0 = ((float4*)&sw[n][0])[mg*2];
      float4 w1 = ((float4*)&sw[n][0])[mg*2+1];
      float4 f0 = ((float4*)&sf[n][0])[cg*2];
      float4 f1 = ((float4*)&sf[n][0])[cg*2+1];
      float wv[8] = {w0.x,w0.y,w0.z,w0.w,w1.x,w1.y,w1.z,w1.w};
      float fv[8] = {f0.x,f0.y,f0.z,f0.w,f1.x,f1.y,f1.z,f1.w};
#pragma unroll
      for (int a = 0; a < 8; ++a)
#pragma unroll
        for (int b2 = 0; b2 < 8; ++b2) acc[a][b2] = fmaf(wv[a], fv[b2], acc[a][b2]);
    }
  }
  for (int a = 0; a < 8; ++a) {
    int m = mt*64 + mg*8 + a;
    float* dst = &part[((size_t)nc*MP + m)*128 + cg*8];
    ((float4*)dst)[0] = make_float4(acc[a][0], acc[a][1], acc[a][2], acc[a][3]);
    ((float4*)dst)[1] = make_float4(acc[a][4], acc[a][5], acc[a][6], acc[a][7]);
  }
}

__global__ void k_pfeat_red(const float* __restrict__ part, const float* __restrict__ pf,
                            float* __restrict__ p1) {
  int idx = blockIdx.x*256 + threadIdx.x;
  float s = 0.0f;
  for (int ncb = 0; ncb < 64; ++ncb) s += part[(size_t)ncb*MP*128 + idx];
  p1[idx] = 0.5f*pf[idx] + 0.5f*s;
}

// sim column + top-20 aggregation -> p2
__global__ void k_simtopk(const float* __restrict__ p1, float* __restrict__ p2) {
  const int m = blockIdx.x, t = threadIdx.x;
  __shared__ float spm[128];
  __shared__ float scol[MP];
  __shared__ float sval[20];
  __shared__ int   sid[20];
  __shared__ float sredv[2];
  __shared__ int   sredi[2];
  __shared__ float sden;
  spm[t] = p1[m*128 + t];
  __syncthreads();
  for (int kk = t; kk < MP; kk += 128) {
    float a = 0.0f;
    const float* row = &p1[kk*128];
#pragma unroll 8
    for (int c2 = 0; c2 < 128; ++c2) a = fmaf(row[c2], spm[c2], a);
    scol[kk] = a * SCF;
  }
  __syncthreads();
  for (int rs = 0; rs < 20; ++rs) {
    float bv = -1e30f; int bI = 1 << 30;
    for (int kk = t; kk < MP; kk += 128) {
      float v = scol[kk];
      if (v > bv) { bv = v; bI = kk; }
    }
#pragma unroll
    for (int off = 32; off > 0; off >>= 1) {
      float ov = __shfl_down(bv, off); int oi = __shfl_down(bI, off);
      if (ov > bv || (ov == bv && oi < bI)) { bv = ov; bI = oi; }
    }
    if ((t & 63) == 0) { sredv[t>>6] = bv; sredi[t>>6] = bI; }
    __syncthreads();
    if (t == 0) {
      float v1 = sredv[1]; int i1 = sredi[1];
      if (v1 > bv || (v1 == bv && i1 < bI)) { bv = v1; bI = i1; }
      sval[rs] = bv; sid[rs] = bI;
      scol[bI] = -1e30f;
    }
    __syncthreads();
  }
  if (t == 0) {
    float s = 0.0f;
    for (int rs = 0; rs < 20; ++rs) s += sval[rs];
    sden = fmaxf(s, 1e-4f);
  }
  __syncthreads();
  float a = 0.0f;
  float den = sden;
  for (int rs = 0; rs < 20; ++rs) {
    float w = sval[rs] / den;
    a = fmaf(w, p1[sid[rs]*128 + t], a);
  }
  p2[m*128 + t] = 0.5f*p1[m*128 + t] + 0.5f*a;
}

// sim_pt = feats @ p2^T * sc (stored fp16) : grid (1024, 8), block 256
__global__ void k_simpt(const float* __restrict__ feats, const float* __restrict__ p2,
                        __half* __restrict__ sim) {
  const int t = threadIdx.x;
  const int nt = blockIdx.x;
  const int mt = blockIdx.y;
  __shared__ float sa[64][68];
  __shared__ float sb[64][68];
  const int tn = t >> 4, tm = t & 15;
  float acc[4][4];
#pragma unroll
  for (int x = 0; x < 4; ++x)
#pragma unroll
    for (int y = 0; y < 4; ++y) acc[x][y] = 0.0f;
  for (int kh = 0; kh < 2; ++kh) {
    __syncthreads();
    for (int q2 = t; q2 < 1024; q2 += 256) {
      int row = q2 >> 4, c4 = q2 & 15;
      ((float4*)&sa[row][0])[c4] =
          ((const float4*)feats)[(size_t)(nt*64+row)*32 + kh*16 + c4];
      ((float4*)&sb[row][0])[c4] =
          ((const float4*)p2)[(size_t)(mt*64+row)*32 + kh*16 + c4];
    }
    __syncthreads();
    for (int k = 0; k < 64; ++k) {
      float av[4], bv[4];
#pragma unroll
      for (int x = 0; x < 4; ++x) av[x] = sa[tn*4+x][k];
#pragma unroll
      for (int y = 0; y < 4; ++y) bv[y] = sb[tm*4+y][k];
#pragma unroll
      for (int x = 0; x < 4; ++x)
#pragma unroll
        for (int y = 0; y < 4; ++y) acc[x][y] = fmaf(av[x], bv[y], acc[x][y]);
    }
  }
  for (int x = 0; x < 4; ++x)
    for (int y = 0; y < 4; ++y) {
      int n = nt*64 + tn*4 + x, mc = mt*64 + tm*4 + y;
      sim[(size_t)n*MP + mc] = __float2half(acc[x][y] * SCF);
    }
}

// fused factorized sinkhorn 2 over E2: 64 blocks x 1024 thr, 1 barrier/iter.
// V_i = ebn_i + sum_j E2*C_j; R=1/V; outputs R (rr_out) and C (c_out).
__global__ __launch_bounds__(1024) void k_sk2(const unsigned short* __restrict__ E2,
                                              const float* __restrict__ ebn,
                                              float* __restrict__ rr_out,
                                              float* __restrict__ c_out,
                                              float* __restrict__ partbuf,
                                              int* __restrict__ slots) {
  const int t = threadIdx.x, b = blockIdx.x;
  __shared__ float sC[MP];
  __shared__ float sRr[1024];
  __shared__ float scol[MP];
  if (t < MP) sC[t] = 1.0f;
  __syncthreads();
  const int row = b * 1024 + t;
  const us8* e8 = (const us8*)(E2 + (size_t)row * MP);
  const float eb = ebn[row];
  const int ct = t & 511, rh = t >> 9;
  for (int it = 0; it < SKI; ++it) {
    float V = eb;
    for (int g0 = 0; g0 < 64; g0 += 8) {
      us8 u[8];
#pragma unroll
      for (int g = 0; g < 8; ++g) u[g] = e8[g0 + g];
#pragma unroll
      for (int g = 0; g < 8; ++g)
#pragma unroll
        for (int e = 0; e < 8; ++e)
          V = fmaf(h2f(u[g][e]), sC[(g0+g)*8 + e], V);
    }
    float R = 1.0f / V;
    sRr[t] = R;
    __syncthreads();
    float S = 0.0f;
    const int r0 = rh * 512;
    for (int k0 = 0; k0 < 512; k0 += 8) {
      float v[8];
#pragma unroll
      for (int u2 = 0; u2 < 8; ++u2)
        v[u2] = h2f(E2[(size_t)(b*1024 + r0 + k0 + u2) * MP + ct]);
#pragma unroll
      for (int u2 = 0; u2 < 8; ++u2)
        S = fmaf(v[u2], sRr[r0 + k0 + u2], S);
    }
    if (rh == 1) scol[ct] = S;
    __syncthreads();
    if (rh == 0) {
      S += scol[ct];
      pub_f32(&partbuf[((it & 1) << 15) + (ct << 6) + b], S);
    }
    gbar(slots, it + 1, b, t);
    if (t < MP) {
      const float* pb = &partbuf[((it & 1) << 15) + (t << 6)];
      float Sm = 0.0f;
      for (int q = 0; q < SKB2; ++q) Sm += rd_f32(&pb[q]);
      sC[t] = 1.0f / (Sm + 1.0f);
    }
    __syncthreads();
  }
  rr_out[row] = sRr[t];
  if (b == 0 && t < MP) c_out[t] = sC[t];
}

// refined = 0.5*feats + 0.5 * w @ p2, w = E2 * R_i * C_j
__global__ void k_refined(const unsigned short* __restrict__ E2,
                          const float* __restrict__ rr, const float* __restrict__ cc,
                          const float* __restrict__ p2,
                          const float* __restrict__ feats, float* __restrict__ out) {
  const int t = threadIdx.x;
  const int nb = blockIdx.x;  // 64 rows per block
  __shared__ float sp[64][128];
  __shared__ float sw[64][68];
  __shared__ float srr[64], scc[64];
  const int tn = t >> 5, tc = t & 31;
  if (t < 64) srr[t] = rr[nb*64 + t];
  float acc[8][4];
#pragma unroll
  for (int a = 0; a < 8; ++a)
#pragma unroll
    for (int b2 = 0; b2 < 4; ++b2) acc[a][b2] = 0.0f;
  for (int mt2 = 0; mt2 < 8; ++mt2) {
    __syncthreads();
    for (int q2 = t; q2 < 2048; q2 += 256) {
      int row = q2 >> 5, c4 = q2 & 31;
      ((float4*)&sp[row][0])[c4] = ((const float4*)p2)[(size_t)(mt2*64+row)*32 + c4];
    }
    if (t < 64) scc[t] = cc[mt2*64 + t];
    __syncthreads();
    for (int q2 = t; q2 < 4096; q2 += 256) {
      int nl = q2 >> 6, ml = q2 & 63;
      float ev = h2f(E2[(size_t)(nb*64+nl)*MP + mt2*64 + ml]);
      sw[nl][ml] = ev * srr[nl] * scc[ml];
    }
    __syncthreads();
    for (int mm2 = 0; mm2 < 64; ++mm2) {
      float4 pv = ((float4*)&sp[mm2][0])[tc];
      float wv[8];
#pragma unroll
      for (int a = 0; a < 8; ++a) wv[a] = sw[tn*8+a][mm2];
#pragma unroll
      for (int a = 0; a < 8; ++a) {
        acc[a][0] = fmaf(wv[a], pv.x, acc[a][0]);
        acc[a][1] = fmaf(wv[a], pv.y, acc[a][1]);
        acc[a][2] = fmaf(wv[a], pv.z, acc[a][2]);
        acc[a][3] = fmaf(wv[a], pv.w, acc[a][3]);
      }
    }
  }
  for (int a = 0; a < 8; ++a) {
    int row = nb*64 + tn*8 + a;
    float4 f = ((const float4*)feats)[(size_t)row*32 + tc];
    float4 o;
    o.x = 0.5f*f.x + 0.5f*acc[a][0];
    o.y = 0.5f*f.y + 0.5f*acc[a][1];
    o.z = 0.5f*f.z + 0.5f*acc[a][2];
    o.w = 0.5f*f.w + 0.5f*acc[a][3];
    ((float4*)out)[(size_t)row*32 + tc] = o;
  }
}

// ---------------- launcher ----------------

extern "C" void kernel_launch(void* const* d_in, const int* in_sizes, int n_in,
                              void* d_out, int out_size, void* d_ws, size_t ws_size,
                              hipStream_t stream) {
  (void)in_sizes; (void)n_in; (void)out_size; (void)ws_size;
  const float* xyz   = (const float*)d_in[0];
  const float* feats = (const float*)d_in[1];
  float* out = (float*)d_out;
  char* ws = (char*)d_ws;

  auto al = [](size_t x) { return (x + 255) & ~(size_t)255; };
  // E-buffer (fp16, 64MB): holds E1 (sk1/pfeat), later overwritten by sim -> E2
  unsigned short* Ebuf = (unsigned short*)ws;
  size_t o = al((size_t)NP * MP * 2);
  float4* xyzs4 = (float4*)(ws + o); o += al((size_t)NP * 16);
  float* rbuf   = (float*)(ws + o);  o += al((size_t)NP * 4);
  float* ebnbuf = (float*)(ws + o);  o += al((size_t)NP * 4);
  float* cbuf   = (float*)(ws + o);  o += al((size_t)MP * 4);
  float* gcbuf  = (float*)(ws + o);  o += al((size_t)MP * 4);
  int*   cent   = (int*)(ws + o);    o += al((size_t)MP * 4);
  float4* pxyzs4 = (float4*)(ws + o); o += al((size_t)MP * 16);
  float* ge     = (float*)(ws + o);  o += al((size_t)MP * 4);
  float* meann  = (float*)(ws + o);  o += al((size_t)256);
  float* pf     = (float*)(ws + o);  o += al((size_t)MP * 128 * 4);
  float* p1     = (float*)(ws + o);  o += al((size_t)MP * 128 * 4);
  float* p2     = (float*)(ws + o);  o += al((size_t)MP * 128 * 4);
  float* partbuf = (float*)(ws + o); o += al((size_t)2 * MP * SKB2 * 4);
  unsigned long long* fslots = (unsigned long long*)(ws + o);
  o += al((size_t)3 * FNB * 8);
  int* bar1 = (int*)(ws + o); o += al((size_t)256);
  int* bar2 = (int*)(ws + o); o += al((size_t)256);
  float* partA = (float*)(ws + o); o += al((size_t)64 * MP * 128 * 4);

  k_init<<<dim3(1), dim3(256), 0, stream>>>(fslots, bar1, bar2);
  k_prep<<<dim3(256), dim3(256), 0, stream>>>(xyz, xyzs4);
  k_fps3<<<dim3(FNB), dim3(256), 0, stream>>>(xyzs4, cent, fslots);
  k_gather1<<<dim3(1), dim3(512), 0, stream>>>(xyz, cent, pxyzs4, meann);
  k_gatherf<<<dim3(512), dim3(128), 0, stream>>>(feats, cent, pf);
  k_ballpca<<<dim3(512), dim3(256), 0, stream>>>(xyzs4, pxyzs4, meann, ge);

  // sinkhorn 1 on precomputed E1 (factorized, exp-free, fence-free)
  k_e1<<<dim3(512), dim3(256), 0, stream>>>(xyzs4, pxyzs4, Ebuf);
  k_sk1<<<dim3(SKB2), dim3(1024), 0, stream>>>(Ebuf, ge, rbuf, gcbuf, partbuf, bar1);

  k_pfeat_part<<<dim3(64, 8), dim3(128), 0, stream>>>(Ebuf, gcbuf, rbuf, feats, partA);
  k_pfeat_red<<<dim3(256), dim3(256), 0, stream>>>(partA, pf, p1);
  k_simtopk<<<dim3(512), dim3(128), 0, stream>>>(p1, p2);

  // sim -> E2 (in place) -> sinkhorn 2 -> refined
  k_simpt<<<dim3(1024, 8), dim3(256), 0, stream>>>(feats, p2, (__half*)Ebuf);
  k_e2<<<dim3(256), dim3(256), 0, stream>>>(Ebuf, ebnbuf);
  k_sk2<<<dim3(SKB2), dim3(1024), 0, stream>>>(Ebuf, ebnbuf, rbuf, cbuf, partbuf, bar2);
  k_refined<<<dim3(1024), dim3(256), 0, stream>>>(Ebuf, rbuf, cbuf, p2, feats, out);
}

// Round 8
// 4187.711 us; speedup vs baseline: 2.8817x; 1.1940x over previous
//
#include <hip/hip_runtime.h>
#include <hip/hip_fp16.h>
#include <math.h>

#define NP 65536
#define MP 512
#define SKI 20
#define NBALL 10

#define FNB 16      // fps blocks
#define FPT 512     // fps threads per block
#define SKB2 64     // sinkhorn blocks

// f32(-1/0.05f) rounds exactly to -20.0f
#define NINV_TAU (-20.0f)
// 1/f32(sqrt(128)) ; sc = 1/sqrt(C)
#define SCF (1.0f / 11.313708305358886719f)
#define SCNT (SCF * NINV_TAU)

typedef unsigned short us8 __attribute__((ext_vector_type(8)));

// ---------------- helpers ----------------

__device__ __forceinline__ float h2f(unsigned short u) {
  return __half2float(__builtin_bit_cast(__half, u));
}
__device__ __forceinline__ unsigned short f2h(float f) {
  return __builtin_bit_cast(unsigned short, __float2half(f));
}

__device__ __forceinline__ float rd_f32(const float* p) {
  return __uint_as_float(__hip_atomic_load((const unsigned int*)p,
                                           __ATOMIC_RELAXED,
                                           __HIP_MEMORY_SCOPE_AGENT));
}

// fence-free barrier: release epoch store + acquire poll (R7-proven).
__device__ __forceinline__ void gbar(int* slots, int ep, int b, int t) {
  __syncthreads();
  if (t == 0) {
    __hip_atomic_store(&slots[b], ep, __ATOMIC_RELEASE, __HIP_MEMORY_SCOPE_AGENT);
  }
  if (t < SKB2) {
    while (__hip_atomic_load(&slots[t], __ATOMIC_ACQUIRE,
                             __HIP_MEMORY_SCOPE_AGENT) < ep) {}
  }
  __syncthreads();
}

// closed-form symmetric 3x3 eigenvalues (ascending), double precision
__device__ void eig3(double a00, double a01, double a02, double a11, double a12,
                     double a22, double* e) {
  double p1 = a01*a01 + a02*a02 + a12*a12;
  double q  = (a00 + a11 + a22) / 3.0;
  double b00 = a00 - q, b11 = a11 - q, b22 = a22 - q;
  double p2 = b00*b00 + b11*b11 + b22*b22 + 2.0*p1;
  if (p2 <= 1e-300) { e[0] = e[1] = e[2] = q; return; }
  double p = sqrt(p2 / 6.0);
  double ip = 1.0 / p;
  double c00 = b00*ip, c01 = a01*ip, c02 = a02*ip;
  double c11 = b11*ip, c12 = a12*ip, c22 = b22*ip;
  double detB = c00*(c11*c22 - c12*c12) - c01*(c01*c22 - c12*c02)
              + c02*(c01*c12 - c11*c02);
  double r = detB / 2.0;
  r = fmin(1.0, fmax(-1.0, r));
  double phi = acos(r) / 3.0;
  double e2 = q + 2.0*p*cos(phi);
  double e0 = q + 2.0*p*cos(phi + 2.0943951023931953);
  double e1 = 3.0*q - e2 - e0;
  e[0] = e0; e[1] = e1; e[2] = e2;
}

// ---------------- kernels ----------------

__global__ void k_init(unsigned long long* __restrict__ slots, int* __restrict__ bar1,
                       int* __restrict__ bar2) {
  int t = threadIdx.x;
  if (t < 3 * FNB) slots[t] = 0ULL;
  if (t < SKB2) { bar1[t] = 0; bar2[t] = 0; }
}

// pack xyz + |x|^2 into float4
__global__ void k_prep(const float* __restrict__ xyz, float4* __restrict__ xyzs4) {
  int i = blockIdx.x * blockDim.x + threadIdx.x;
  if (i < NP) {
    float x = xyz[3*i+0], y = xyz[3*i+1], z = xyz[3*i+2];
    xyzs4[i] = make_float4(x, y, z, x*x + y*y + z*z);
  }
}

// FPS: 16 blocks x 512 threads, 8 pts/thread in regs. Payload slot barrier,
// mod-3 phase buffering.
__global__ __launch_bounds__(FPT) void k_fps3(const float4* __restrict__ xyzs4,
                                              int* __restrict__ cent,
                                              unsigned long long* __restrict__ slots) {
  const int t = threadIdx.x, b = blockIdx.x;
  const int base = (b * FPT + t) * 8;
  float X[8], Y[8], Z[8], D[8];
#pragma unroll
  for (int k = 0; k < 8; ++k) {
    float4 p = xyzs4[base + k];
    X[k] = p.x; Y[k] = p.y; Z[k] = p.z; D[k] = 1e10f;
  }
  __shared__ unsigned long long swave[8];
  __shared__ unsigned long long swin;
  int cur = 0;
  float cx = xyzs4[0].x, cy = xyzs4[0].y, cz = xyzs4[0].z;
  const int lane = t & 63, wid = t >> 6;
  for (int it = 0; it < MP; ++it) {
    if (b == 0 && t == 0) cent[it] = cur;
    float bm = -1.0f; int bi = 0x7fffffff;
#pragma unroll
    for (int k = 0; k < 8; ++k) {
      float dx = X[k] - cx, dy = Y[k] - cy, dz = Z[k] - cz;
      float d = dx*dx + dy*dy + dz*dz;
      float nd = fminf(D[k], d);
      D[k] = nd;
      bool gt = (nd > bm);
      bi = gt ? (base + k) : bi;
      bm = gt ? nd : bm;
    }
    unsigned long long key =
        ((unsigned long long)__float_as_uint(bm) << 32) |
        (unsigned int)(0x7fffffff - bi);
#pragma unroll
    for (int off = 32; off > 0; off >>= 1) {
      unsigned long long o = __shfl_down(key, off);
      key = (o > key) ? o : key;
    }
    if (lane == 0) swave[wid] = key;
    __syncthreads();
    const int p = it % 3, pn = (it + 1) % 3;
    if (t == 0) {
      unsigned long long k0 = swave[0];
      for (int w = 1; w < 8; ++w) k0 = (swave[w] > k0) ? swave[w] : k0;
      __hip_atomic_store(&slots[pn * FNB + b], 0ULL, __ATOMIC_RELAXED,
                         __HIP_MEMORY_SCOPE_AGENT);
      __hip_atomic_store(&slots[p * FNB + b], k0, __ATOMIC_RELEASE,
                         __HIP_MEMORY_SCOPE_AGENT);
    }
    if (wid == 0) {
      unsigned long long v = 0ULL;
      if (lane < FNB) {
        do {
          v = __hip_atomic_load(&slots[p * FNB + lane], __ATOMIC_ACQUIRE,
                                __HIP_MEMORY_SCOPE_AGENT);
        } while (v == 0ULL);
      }
#pragma unroll
      for (int off = 32; off > 0; off >>= 1) {
        unsigned long long o = __shfl_down(v, off);
        v = (o > v) ? o : v;
      }
      if (lane == 0) swin = v;
    }
    __syncthreads();
    unsigned long long wkey = swin;
    cur = 0x7fffffff - (int)(wkey & 0xffffffffu);
    float4 cc = xyzs4[cur];
    cx = cc.x; cy = cc.y; cz = cc.z;
    __syncthreads();
  }
}

// gather proto xyz (+norm) and mean node
__global__ void k_gather1(const float* __restrict__ xyz, const int* __restrict__ cent,
                          float4* __restrict__ pxyzs4, float* __restrict__ meann) {
  __shared__ float sx[512], sy[512], sz[512];
  int m = threadIdx.x;
  int c = cent[m];
  float x = xyz[3*c+0], y = xyz[3*c+1], z = xyz[3*c+2];
  pxyzs4[m] = make_float4(x, y, z, x*x + y*y + z*z);
  sx[m] = x; sy[m] = y; sz[m] = z;
  __syncthreads();
  for (int off = 256; off > 0; off >>= 1) {
    if (m < off) { sx[m] += sx[m+off]; sy[m] += sy[m+off]; sz[m] += sz[m+off]; }
    __syncthreads();
  }
  if (m == 0) {
    meann[0] = sx[0] * (1.0f/512.0f);
    meann[1] = sy[0] * (1.0f/512.0f);
    meann[2] = sz[0] * (1.0f/512.0f);
  }
}

// gather proto features
__global__ void k_gatherf(const float* __restrict__ feats, const int* __restrict__ cent,
                          float* __restrict__ pf) {
  int m = blockIdx.x, c = threadIdx.x;
  pf[m*128 + c] = feats[(size_t)cent[m]*128 + c];
}

// ball query (first 10 smallest indices within radius) + PCA curvature -> dist_ge
__global__ void k_ballpca(const float4* __restrict__ xyzs4,
                          const float4* __restrict__ pxyzs4,
                          const float* __restrict__ meann,
                          float* __restrict__ ge) {
  const int m = blockIdx.x, t = threadIdx.x;
  __shared__ int lidx[256][NBALL];
  __shared__ int s_sel[NBALL];
  __shared__ int s_win;
  __shared__ int s_w4[4];
  float4 q = pxyzs4[m];
  int cnt = 0;
  for (int k = 0; k < 256; ++k) {
    int i = (k << 8) + t;
    float4 p = xyzs4[i];
    float dot = q.x*p.x + q.y*p.y + q.z*p.z;
    float d2 = (q.w + p.w) - 2.0f*dot;
    float d = sqrtf(fmaxf(d2, 0.0f));
    if (!(d > 0.04f) && cnt < NBALL) { lidx[t][cnt] = i; cnt++; }
  }
  __syncthreads();
  int hp = 0;
  for (int r = 0; r < NBALL; ++r) {
    int v = (hp < cnt) ? lidx[t][hp] : 0x7fffffff;
#pragma unroll
    for (int off = 32; off > 0; off >>= 1) v = min(v, __shfl_down(v, off));
    if ((t & 63) == 0) s_w4[t >> 6] = v;
    __syncthreads();
    if (t == 0) s_win = min(min(s_w4[0], s_w4[1]), min(s_w4[2], s_w4[3]));
    __syncthreads();
    int w = s_win;
    if (w != 0x7fffffff && hp < cnt && lidx[t][hp] == w) hp++;
    if (t == 0) s_sel[r] = w;
    __syncthreads();
  }
  if (t == 0) {
    float mx = meann[0], my = meann[1], mz = meann[2];
    int first = (s_sel[0] != 0x7fffffff) ? s_sel[0] : NP;
    float c00=0,c01=0,c02=0,c11=0,c12=0,c22=0;
    for (int r = 0; r < NBALL; ++r) {
      int id = s_sel[r];
      if (id == 0x7fffffff) id = first;
      float nx, ny, nz;
      if (id >= NP) { nx = mx; ny = my; nz = mz; }
      else { float4 p = xyzs4[id]; nx = p.x; ny = p.y; nz = p.z; }
      float dx = nx - q.x, dy = ny - q.y, dz = nz - q.z;
      c00 += dx*dx; c01 += dx*dy; c02 += dx*dz;
      c11 += dy*dy; c12 += dy*dz; c22 += dz*dz;
    }
    double e[3];
    eig3((double)(c00/10.0f + 1e-8f), (double)(c01/10.0f + 1e-8f),
         (double)(c02/10.0f + 1e-8f), (double)(c11/10.0f + 1e-8f),
         (double)(c12/10.0f + 1e-8f), (double)(c22/10.0f + 1e-8f), e);
    float l0 = (float)e[0], l1 = (float)e[1], l2r = (float)e[2];
    float l2 = fmaxf(l2r, 1e-8f);
    float f0 = (l2 - l1) / l2, f1 = (l1 - l0) / l2, f2 = l0 / l2;
    ge[m] = sqrtf(f0*f0 + f1*f1 + f2*f2) / sqrtf(3.0f);
  }
}

// E1 = fp16(exp(dist(i,j) * SCNT)); 512 blocks x 256 thr; 2 thr/row, 256 cols each
__global__ void k_e1(const float4* __restrict__ xyzs4,
                     const float4* __restrict__ pxyzs4,
                     unsigned short* __restrict__ E1) {
  const int t = threadIdx.x, b = blockIdx.x;
  __shared__ float4 spp[MP];
  spp[t] = pxyzs4[t];
  spp[t + 256] = pxyzs4[t + 256];
  __syncthreads();
  const int row = b * 128 + (t >> 1);
  const int h = t & 1;
  const float4 q = xyzs4[row];
  us8* dst = (us8*)(E1 + (size_t)row * MP + h * 256);
  for (int g = 0; g < 32; ++g) {
    us8 v;
#pragma unroll
    for (int e = 0; e < 8; ++e) {
      float4 p = spp[h*256 + g*8 + e];
      float dot = q.x*p.x + q.y*p.y + q.z*p.z;
      float dist = sqrtf(fmaxf((q.w + p.w) - 2.0f*dot, 0.0f));
      v[e] = f2h(__expf(dist * SCNT));
    }
    dst[g] = v;
  }
}

// in-place transform: sim(fp16) -> E2 = fp16(exp(sim*NT - B_row)); ebn = exp(-B)
__global__ void k_e2(unsigned short* __restrict__ sim, float* __restrict__ ebn) {
  const int row = blockIdx.x * blockDim.x + threadIdx.x;
  us8* v8 = (us8*)(sim + (size_t)row * MP);
  float B = -1e30f;
  for (int g = 0; g < 64; ++g) {
    us8 u = v8[g];
#pragma unroll
    for (int e = 0; e < 8; ++e) B = fmaxf(B, h2f(u[e]) * NINV_TAU);
  }
  ebn[row] = __expf(-B);
  for (int g = 0; g < 64; ++g) {
    us8 u = v8[g];
    us8 w;
#pragma unroll
    for (int e = 0; e < 8; ++e) w[e] = f2h(__expf(h2f(u[e]) * NINV_TAU - B));
    v8[g] = w;
  }
}

// fused factorized sinkhorn 1: 64 blocks x 1024 thr, 1 barrier/iter.
// Col sums via per-column fp32 atomicAdd into colsum[it][col].
__global__ __launch_bounds__(1024) void k_sk1(const unsigned short* __restrict__ E1,
                                              const float* __restrict__ ge,
                                              float* __restrict__ rr_out,
                                              float* __restrict__ gc_out,
                                              float* __restrict__ colsum,
                                              int* __restrict__ slots) {
  const int t = threadIdx.x, b = blockIdx.x;
  __shared__ float sG[MP];
  __shared__ float sGC[MP];
  __shared__ float sRr[1024];
  __shared__ float scol[MP];
  if (t < MP) {
    float g = __expf(ge[t] * NINV_TAU);
    sG[t] = g;
    sGC[t] = g;   // C^0 = 1
  }
  __syncthreads();
  const int row = b * 1024 + t;
  const us8* e8 = (const us8*)(E1 + (size_t)row * MP);
  const int ct = t & 511, rh = t >> 9;
  for (int it = 0; it < SKI; ++it) {
    // ---- row: V = 1 + sum_j E1_ij * (G_j C_j) ----
    float V = 1.0f;
    for (int g0 = 0; g0 < 64; g0 += 8) {
      us8 u[8];
#pragma unroll
      for (int g = 0; g < 8; ++g) u[g] = e8[g0 + g];
#pragma unroll
      for (int g = 0; g < 8; ++g)
#pragma unroll
        for (int e = 0; e < 8; ++e)
          V = fmaf(h2f(u[g][e]), sGC[(g0+g)*8 + e], V);
    }
    float Rr = 1.0f / V;
    sRr[t] = Rr;
    __syncthreads();
    // ---- col partial over slab: S_j = sum_i E1_ij * Rr_i ----
    float S = 0.0f;
    const int r0 = rh * 512;
    for (int k0 = 0; k0 < 512; k0 += 8) {
      float v[8];
#pragma unroll
      for (int u2 = 0; u2 < 8; ++u2)
        v[u2] = h2f(E1[(size_t)(b*1024 + r0 + k0 + u2) * MP + ct]);
#pragma unroll
      for (int u2 = 0; u2 < 8; ++u2)
        S = fmaf(v[u2], sRr[r0 + k0 + u2], S);
    }
    if (rh == 1) scol[ct] = S;
    __syncthreads();
    if (rh == 0) {
      S += scol[ct];
      __hip_atomic_fetch_add(&colsum[it * MP + ct], S, __ATOMIC_RELAXED,
                             __HIP_MEMORY_SCOPE_AGENT);
    }
    gbar(slots, it + 1, b, t);
    // ---- new C from summed column ----
    if (t < MP) {
      float Sm = rd_f32(&colsum[it * MP + t]);
      float Cj = 1.0f / fmaf(sG[t], Sm, 1.0f);
      sGC[t] = sG[t] * Cj;
    }
    __syncthreads();
  }
  rr_out[row] = sRr[t];
  if (b == 0 && t < MP) gc_out[t] = sGC[t];
}

// partial gamma^T @ feats using E1: gamma = E1 * gc_j * rr_i
__global__ void k_pfeat_part(const unsigned short* __restrict__ E1,
                             const float* __restrict__ gc, const float* __restrict__ rr,
                             const float* __restrict__ feats,
                             float* __restrict__ part) {
  const int t = threadIdx.x;
  const int nc = blockIdx.x;
  const int mt = blockIdx.y;
  __shared__ float sgc[64];
  __shared__ float sf[64][128];
  __shared__ float sw[64][64];
  __shared__ float srr[64];
  if (t < 64) sgc[t] = gc[mt*64 + t];
  const int mg = t >> 4;
  const int cg = t & 15;
  float acc[8][8];
#pragma unroll
  for (int a = 0; a < 8; ++a)
#pragma unroll
    for (int b2 = 0; b2 < 8; ++b2) acc[a][b2] = 0.0f;
  for (int bt = 0; bt < 16; ++bt) {
    int n0 = nc*1024 + bt*64;
    __syncthreads();
    for (int q2 = t; q2 < 2048; q2 += 128) {
      int row = q2 >> 5, c4 = q2 & 31;
      ((float4*)&sf[row][0])[c4] = ((const float4*)feats)[(size_t)(n0+row)*32 + c4];
    }
    if (t < 64) srr[t] = rr[n0 + t];
    __syncthreads();
    for (int q2 = t; q2 < 4096; q2 += 128) {
      int nl = q2 >> 6, ml = q2 & 63;
      float ev = h2f(E1[(size_t)(n0+nl)*MP + mt*64 + ml]);
      sw[nl][ml] = ev * sgc[ml] * srr[nl];
    }
    __syncthreads();
#pragma unroll 8
    for (int n = 0; n < 64; ++n) {
      float4 w0 = ((float4*)&sw[n][0])[mg*2];
      float4 w1 = ((float4*)&sw[n][0])[mg*2+1];
      float4 f0 = ((float4*)&sf[n][0])[cg*2];
      float4 f1 = ((float4*)&sf[n][0])[cg*2+1];
      float wv[8] = {w0.x,w0.y,w0.z,w0.w,w1.x,w1.y,w1.z,w1.w};
      float fv[8] = {f0.x,f0.y,f0.z,f0.w,f1.x,f1.y,f1.z,f1.w};
#pragma unroll
      for (int a = 0; a < 8; ++a)
#pragma unroll
        for (int b2 = 0; b2 < 8; ++b2) acc[a][b2] = fmaf(wv[a], fv[b2], acc[a][b2]);
    }
  }
  for (int a = 0; a < 8; ++a) {
    int m = mt*64 + mg*8 + a;
    float* dst = &part[((size_t)nc*MP + m)*128 + cg*8];
    ((float4*)dst)[0] = make_float4(acc[a][0], acc[a][1], acc[a][2], acc[a][3]);
    ((float4*)dst)[1] = make_float4(acc[a][4], acc[a][5], acc[a][6], acc[a][7]);
  }
}

__global__ void k_pfeat_red(const float* __restrict__ part, const float* __restrict__ pf,
                            float* __restrict__ p1) {
  int idx = blockIdx.x*256 + threadIdx.x;
  float s = 0.0f;
  for (int ncb = 0; ncb < 64; ++ncb) s += part[(size_t)ncb*MP*128 + idx];
  p1[idx] = 0.5f*pf[idx] + 0.5f*s;
}

// sim column + top-20 aggregation -> p2
__global__ void k_simtopk(const float* __restrict__ p1, float* __restrict__ p2) {
  const int m = blockIdx.x, t = threadIdx.x;
  __shared__ float spm[128];
  __shared__ float scol[MP];
  __shared__ float sval[20];
  __shared__ int   sid[20];
  __shared__ float sredv[2];
  __shared__ int   sredi[2];
  __shared__ float sden;
  spm[t] = p1[m*128 + t];
  __syncthreads();
  for (int kk = t; kk < MP; kk += 128) {
    float a = 0.0f;
    const float* row = &p1[kk*128];
#pragma unroll 8
    for (int c2 = 0; c2 < 128; ++c2) a = fmaf(row[c2], spm[c2], a);
    scol[kk] = a * SCF;
  }
  __syncthreads();
  for (int rs = 0; rs < 20; ++rs) {
    float bv = -1e30f; int bI = 1 << 30;
    for (int kk = t; kk < MP; kk += 128) {
      float v = scol[kk];
      if (v > bv) { bv = v; bI = kk; }
    }
#pragma unroll
    for (int off = 32; off > 0; off >>= 1) {
      float ov = __shfl_down(bv, off); int oi = __shfl_down(bI, off);
      if (ov > bv || (ov == bv && oi < bI)) { bv = ov; bI = oi; }
    }
    if ((t & 63) == 0) { sredv[t>>6] = bv; sredi[t>>6] = bI; }
    __syncthreads();
    if (t == 0) {
      float v1 = sredv[1]; int i1 = sredi[1];
      if (v1 > bv || (v1 == bv && i1 < bI)) { bv = v1; bI = i1; }
      sval[rs] = bv; sid[rs] = bI;
      scol[bI] = -1e30f;
    }
    __syncthreads();
  }
  if (t == 0) {
    float s = 0.0f;
    for (int rs = 0; rs < 20; ++rs) s += sval[rs];
    sden = fmaxf(s, 1e-4f);
  }
  __syncthreads();
  float a = 0.0f;
  float den = sden;
  for (int rs = 0; rs < 20; ++rs) {
    float w = sval[rs] / den;
    a = fmaf(w, p1[sid[rs]*128 + t], a);
  }
  p2[m*128 + t] = 0.5f*p1[m*128 + t] + 0.5f*a;
}

// sim_pt = feats @ p2^T * sc (stored fp16) : grid (1024, 8), block 256
__global__ void k_simpt(const float* __restrict__ feats, const float* __restrict__ p2,
                        __half* __restrict__ sim) {
  const int t = threadIdx.x;
  const int nt = blockIdx.x;
  const int mt = blockIdx.y;
  __shared__ float sa[64][68];
  __shared__ float sb[64][68];
  const int tn = t >> 4, tm = t & 15;
  float acc[4][4];
#pragma unroll
  for (int x = 0; x < 4; ++x)
#pragma unroll
    for (int y = 0; y < 4; ++y) acc[x][y] = 0.0f;
  for (int kh = 0; kh < 2; ++kh) {
    __syncthreads();
    for (int q2 = t; q2 < 1024; q2 += 256) {
      int row = q2 >> 4, c4 = q2 & 15;
      ((float4*)&sa[row][0])[c4] =
          ((const float4*)feats)[(size_t)(nt*64+row)*32 + kh*16 + c4];
      ((float4*)&sb[row][0])[c4] =
          ((const float4*)p2)[(size_t)(mt*64+row)*32 + kh*16 + c4];
    }
    __syncthreads();
    for (int k = 0; k < 64; ++k) {
      float av[4], bv[4];
#pragma unroll
      for (int x = 0; x < 4; ++x) av[x] = sa[tn*4+x][k];
#pragma unroll
      for (int y = 0; y < 4; ++y) bv[y] = sb[tm*4+y][k];
#pragma unroll
      for (int x = 0; x < 4; ++x)
#pragma unroll
        for (int y = 0; y < 4; ++y) acc[x][y] = fmaf(av[x], bv[y], acc[x][y]);
    }
  }
  for (int x = 0; x < 4; ++x)
    for (int y = 0; y < 4; ++y) {
      int n = nt*64 + tn*4 + x, mc = mt*64 + tm*4 + y;
      sim[(size_t)n*MP + mc] = __float2half(acc[x][y] * SCF);
    }
}

// fused factorized sinkhorn 2 over E2: 64 blocks x 1024 thr, 1 barrier/iter.
__global__ __launch_bounds__(1024) void k_sk2(const unsigned short* __restrict__ E2,
                                              const float* __restrict__ ebn,
                                              float* __restrict__ rr_out,
                                              float* __restrict__ c_out,
                                              float* __restrict__ colsum,
                                              int* __restrict__ slots) {
  const int t = threadIdx.x, b = blockIdx.x;
  __shared__ float sC[MP];
  __shared__ float sRr[1024];
  __shared__ float scol[MP];
  if (t < MP) sC[t] = 1.0f;
  __syncthreads();
  const int row = b * 1024 + t;
  const us8* e8 = (const us8*)(E2 + (size_t)row * MP);
  const float eb = ebn[row];
  const int ct = t & 511, rh = t >> 9;
  for (int it = 0; it < SKI; ++it) {
    float V = eb;
    for (int g0 = 0; g0 < 64; g0 += 8) {
      us8 u[8];
#pragma unroll
      for (int g = 0; g < 8; ++g) u[g] = e8[g0 + g];
#pragma unroll
      for (int g = 0; g < 8; ++g)
#pragma unroll
        for (int e = 0; e < 8; ++e)
          V = fmaf(h2f(u[g][e]), sC[(g0+g)*8 + e], V);
    }
    float R = 1.0f / V;
    sRr[t] = R;
    __syncthreads();
    float S = 0.0f;
    const int r0 = rh * 512;
    for (int k0 = 0; k0 < 512; k0 += 8) {
      float v[8];
#pragma unroll
      for (int u2 = 0; u2 < 8; ++u2)
        v[u2] = h2f(E2[(size_t)(b*1024 + r0 + k0 + u2) * MP + ct]);
#pragma unroll
      for (int u2 = 0; u2 < 8; ++u2)
        S = fmaf(v[u2], sRr[r0 + k0 + u2], S);
    }
    if (rh == 1) scol[ct] = S;
    __syncthreads();
    if (rh == 0) {
      S += scol[ct];
      __hip_atomic_fetch_add(&colsum[it * MP + ct], S, __ATOMIC_RELAXED,
                             __HIP_MEMORY_SCOPE_AGENT);
    }
    gbar(slots, it + 1, b, t);
    if (t < MP) {
      float Sm = rd_f32(&colsum[it * MP + t]);
      sC[t] = 1.0f / (Sm + 1.0f);
    }
    __syncthreads();
  }
  rr_out[row] = sRr[t];
  if (b == 0 && t < MP) c_out[t] = sC[t];
}

// refined = 0.5*feats + 0.5 * w @ p2, w = E2 * R_i * C_j
__global__ void k_refined(const unsigned short* __restrict__ E2,
                          const float* __restrict__ rr, const float* __restrict__ cc,
                          const float* __restrict__ p2,
                          const float* __restrict__ feats, float* __restrict__ out) {
  const int t = threadIdx.x;
  const int nb = blockIdx.x;  // 64 rows per block
  __shared__ float sp[64][128];
  __shared__ float sw[64][68];
  __shared__ float srr[64], scc[64];
  const int tn = t >> 5, tc = t & 31;
  if (t < 64) srr[t] = rr[nb*64 + t];
  float acc[8][4];
#pragma unroll
  for (int a = 0; a < 8; ++a)
#pragma unroll
    for (int b2 = 0; b2 < 4; ++b2) acc[a][b2] = 0.0f;
  for (int mt2 = 0; mt2 < 8; ++mt2) {
    __syncthreads();
    for (int q2 = t; q2 < 2048; q2 += 256) {
      int row = q2 >> 5, c4 = q2 & 31;
      ((float4*)&sp[row][0])[c4] = ((const float4*)p2)[(size_t)(mt2*64+row)*32 + c4];
    }
    if (t < 64) scc[t] = cc[mt2*64 + t];
    __syncthreads();
    for (int q2 = t; q2 < 4096; q2 += 256) {
      int nl = q2 >> 6, ml = q2 & 63;
      float ev = h2f(E2[(size_t)(nb*64+nl)*MP + mt2*64 + ml]);
      sw[nl][ml] = ev * srr[nl] * scc[ml];
    }
    __syncthreads();
    for (int mm2 = 0; mm2 < 64; ++mm2) {
      float4 pv = ((float4*)&sp[mm2][0])[tc];
      float wv[8];
#pragma unroll
      for (int a = 0; a < 8; ++a) wv[a] = sw[tn*8+a][mm2];
#pragma unroll
      for (int a = 0; a < 8; ++a) {
        acc[a][0] = fmaf(wv[a], pv.x, acc[a][0]);
        acc[a][1] = fmaf(wv[a], pv.y, acc[a][1]);
        acc[a][2] = fmaf(wv[a], pv.z, acc[a][2]);
        acc[a][3] = fmaf(wv[a], pv.w, acc[a][3]);
      }
    }
  }
  for (int a = 0; a < 8; ++a) {
    int row = nb*64 + tn*8 + a;
    float4 f = ((const float4*)feats)[(size_t)row*32 + tc];
    float4 o;
    o.x = 0.5f*f.x + 0.5f*acc[a][0];
    o.y = 0.5f*f.y + 0.5f*acc[a][1];
    o.z = 0.5f*f.z + 0.5f*acc[a][2];
    o.w = 0.5f*f.w + 0.5f*acc[a][3];
    ((float4*)out)[(size_t)row*32 + tc] = o;
  }
}

// ---------------- launcher ----------------

extern "C" void kernel_launch(void* const* d_in, const int* in_sizes, int n_in,
                              void* d_out, int out_size, void* d_ws, size_t ws_size,
                              hipStream_t stream) {
  (void)in_sizes; (void)n_in; (void)out_size; (void)ws_size;
  const float* xyz   = (const float*)d_in[0];
  const float* feats = (const float*)d_in[1];
  float* out = (float*)d_out;
  char* ws = (char*)d_ws;

  auto al = [](size_t x) { return (x + 255) & ~(size_t)255; };
  // E-buffer (fp16, 64MB): holds E1 (sk1/pfeat), later overwritten by sim -> E2
  unsigned short* Ebuf = (unsigned short*)ws;
  size_t o = al((size_t)NP * MP * 2);
  float4* xyzs4 = (float4*)(ws + o); o += al((size_t)NP * 16);
  float* rbuf   = (float*)(ws + o);  o += al((size_t)NP * 4);
  float* ebnbuf = (float*)(ws + o);  o += al((size_t)NP * 4);
  float* cbuf   = (float*)(ws + o);  o += al((size_t)MP * 4);
  float* gcbuf  = (float*)(ws + o);  o += al((size_t)MP * 4);
  int*   cent   = (int*)(ws + o);    o += al((size_t)MP * 4);
  float4* pxyzs4 = (float4*)(ws + o); o += al((size_t)MP * 16);
  float* ge     = (float*)(ws + o);  o += al((size_t)MP * 4);
  float* meann  = (float*)(ws + o);  o += al((size_t)256);
  float* pf     = (float*)(ws + o);  o += al((size_t)MP * 128 * 4);
  float* p1     = (float*)(ws + o);  o += al((size_t)MP * 128 * 4);
  float* p2     = (float*)(ws + o);  o += al((size_t)MP * 128 * 4);
  float* colsumA = (float*)(ws + o); o += al((size_t)SKI * MP * 4);
  float* colsumB = (float*)(ws + o); o += al((size_t)SKI * MP * 4);
  unsigned long long* fslots = (unsigned long long*)(ws + o);
  o += al((size_t)3 * FNB * 8);
  int* bar1 = (int*)(ws + o); o += al((size_t)256);
  int* bar2 = (int*)(ws + o); o += al((size_t)256);
  float* partA = (float*)(ws + o); o += al((size_t)64 * MP * 128 * 4);

  k_init<<<dim3(1), dim3(256), 0, stream>>>(fslots, bar1, bar2);
  hipMemsetAsync(colsumA, 0, (size_t)2 * SKI * MP * 4 + 256, stream);
  k_prep<<<dim3(256), dim3(256), 0, stream>>>(xyz, xyzs4);
  k_fps3<<<dim3(FNB), dim3(FPT), 0, stream>>>(xyzs4, cent, fslots);
  k_gather1<<<dim3(1), dim3(512), 0, stream>>>(xyz, cent, pxyzs4, meann);
  k_gatherf<<<dim3(512), dim3(128), 0, stream>>>(feats, cent, pf);
  k_ballpca<<<dim3(512), dim3(256), 0, stream>>>(xyzs4, pxyzs4, meann, ge);

  // sinkhorn 1 on precomputed E1 (factorized, exp-free, fence-free)
  k_e1<<<dim3(512), dim3(256), 0, stream>>>(xyzs4, pxyzs4, Ebuf);
  k_sk1<<<dim3(SKB2), dim3(1024), 0, stream>>>(Ebuf, ge, rbuf, gcbuf, colsumA, bar1);

  k_pfeat_part<<<dim3(64, 8), dim3(128), 0, stream>>>(Ebuf, gcbuf, rbuf, feats, partA);
  k_pfeat_red<<<dim3(256), dim3(256), 0, stream>>>(partA, pf, p1);
  k_simtopk<<<dim3(512), dim3(128), 0, stream>>>(p1, p2);

  // sim -> E2 (in place) -> sinkhorn 2 -> refined
  k_simpt<<<dim3(1024, 8), dim3(256), 0, stream>>>(feats, p2, (__half*)Ebuf);
  k_e2<<<dim3(256), dim3(256), 0, stream>>>(Ebuf, ebnbuf);
  k_sk2<<<dim3(SKB2), dim3(1024), 0, stream>>>(Ebuf, ebnbuf, rbuf, cbuf, colsumB, bar2);
  k_refined<<<dim3(1024), dim3(256), 0, stream>>>(Ebuf, rbuf, cbuf, p2, feats, out);
}

// Round 9
// 3820.852 us; speedup vs baseline: 3.1583x; 1.0960x over previous
//
#include <hip/hip_runtime.h>
#include <hip/hip_fp16.h>
#include <math.h>

#define NP 65536
#define MP 512
#define SKI 20
#define NBALL 10

#define FNB 8       // fps blocks
#define FPT 1024    // fps threads per block
#define SKB2 128    // sinkhorn blocks

// f32(-1/0.05f) rounds exactly to -20.0f
#define NINV_TAU (-20.0f)
// 1/f32(sqrt(128)) ; sc = 1/sqrt(C)
#define SCF (1.0f / 11.313708305358886719f)
#define SCNT (SCF * NINV_TAU)

typedef unsigned short us8 __attribute__((ext_vector_type(8)));

// ---------------- helpers ----------------

__device__ __forceinline__ float h2f(unsigned short u) {
  return __half2float(__builtin_bit_cast(__half, u));
}
__device__ __forceinline__ unsigned short f2h(float f) {
  return __builtin_bit_cast(unsigned short, __float2half(f));
}

__device__ __forceinline__ float rd_f32(const float* p) {
  return __uint_as_float(__hip_atomic_load((const unsigned int*)p,
                                           __ATOMIC_RELAXED,
                                           __HIP_MEMORY_SCOPE_AGENT));
}

// fence-free barrier: release epoch store + acquire poll (R7-proven).
__device__ __forceinline__ void gbar(int* slots, int ep, int b, int t) {
  __syncthreads();
  if (t == 0) {
    __hip_atomic_store(&slots[b], ep, __ATOMIC_RELEASE, __HIP_MEMORY_SCOPE_AGENT);
  }
  if (t < SKB2) {
    while (__hip_atomic_load(&slots[t], __ATOMIC_ACQUIRE,
                             __HIP_MEMORY_SCOPE_AGENT) < ep) {}
  }
  __syncthreads();
}

// closed-form symmetric 3x3 eigenvalues (ascending), double precision
__device__ void eig3(double a00, double a01, double a02, double a11, double a12,
                     double a22, double* e) {
  double p1 = a01*a01 + a02*a02 + a12*a12;
  double q  = (a00 + a11 + a22) / 3.0;
  double b00 = a00 - q, b11 = a11 - q, b22 = a22 - q;
  double p2 = b00*b00 + b11*b11 + b22*b22 + 2.0*p1;
  if (p2 <= 1e-300) { e[0] = e[1] = e[2] = q; return; }
  double p = sqrt(p2 / 6.0);
  double ip = 1.0 / p;
  double c00 = b00*ip, c01 = a01*ip, c02 = a02*ip;
  double c11 = b11*ip, c12 = a12*ip, c22 = b22*ip;
  double detB = c00*(c11*c22 - c12*c12) - c01*(c01*c22 - c12*c02)
              + c02*(c01*c12 - c11*c02);
  double r = detB / 2.0;
  r = fmin(1.0, fmax(-1.0, r));
  double phi = acos(r) / 3.0;
  double e2 = q + 2.0*p*cos(phi);
  double e0 = q + 2.0*p*cos(phi + 2.0943951023931953);
  double e1 = 3.0*q - e2 - e0;
  e[0] = e0; e[1] = e1; e[2] = e2;
}

// ---------------- kernels ----------------

// pack xyz + |x|^2 into float4; block 0 also inits barrier/slot state
__global__ void k_prep(const float* __restrict__ xyz, float4* __restrict__ xyzs4,
                       unsigned long long* __restrict__ fslots,
                       int* __restrict__ bar1, int* __restrict__ bar2) {
  int i = blockIdx.x * blockDim.x + threadIdx.x;
  if (i < NP) {
    float x = xyz[3*i+0], y = xyz[3*i+1], z = xyz[3*i+2];
    xyzs4[i] = make_float4(x, y, z, x*x + y*y + z*z);
  }
  if (blockIdx.x == 0) {
    int t = threadIdx.x;
    if (t < 3 * FNB) fslots[t] = 0ULL;
    if (t < SKB2) { bar1[t] = 0; bar2[t] = 0; }
  }
}

// FPS: 8 blocks x 1024 threads, 8 pts/thread in regs. Payload slot barrier,
// mod-3 phase buffering.
__global__ __launch_bounds__(FPT) void k_fps3(const float4* __restrict__ xyzs4,
                                              int* __restrict__ cent,
                                              unsigned long long* __restrict__ slots) {
  const int t = threadIdx.x, b = blockIdx.x;
  const int base = (b * FPT + t) * 8;
  float X[8], Y[8], Z[8], D[8];
#pragma unroll
  for (int k = 0; k < 8; ++k) {
    float4 p = xyzs4[base + k];
    X[k] = p.x; Y[k] = p.y; Z[k] = p.z; D[k] = 1e10f;
  }
  __shared__ unsigned long long swave[16];
  __shared__ unsigned long long swin;
  int cur = 0;
  float cx = xyzs4[0].x, cy = xyzs4[0].y, cz = xyzs4[0].z;
  const int lane = t & 63, wid = t >> 6;
  for (int it = 0; it < MP; ++it) {
    if (b == 0 && t == 0) cent[it] = cur;
    float bm = -1.0f; int bi = 0x7fffffff;
#pragma unroll
    for (int k = 0; k < 8; ++k) {
      float dx = X[k] - cx, dy = Y[k] - cy, dz = Z[k] - cz;
      float d = dx*dx + dy*dy + dz*dz;
      float nd = fminf(D[k], d);
      D[k] = nd;
      bool gt = (nd > bm);
      bi = gt ? (base + k) : bi;
      bm = gt ? nd : bm;
    }
    unsigned long long key =
        ((unsigned long long)__float_as_uint(bm) << 32) |
        (unsigned int)(0x7fffffff - bi);
#pragma unroll
    for (int off = 32; off > 0; off >>= 1) {
      unsigned long long o = __shfl_down(key, off);
      key = (o > key) ? o : key;
    }
    if (lane == 0) swave[wid] = key;
    __syncthreads();
    const int p = it % 3, pn = (it + 1) % 3;
    if (t == 0) {
      unsigned long long k0 = swave[0];
      for (int w = 1; w < 16; ++w) k0 = (swave[w] > k0) ? swave[w] : k0;
      __hip_atomic_store(&slots[pn * FNB + b], 0ULL, __ATOMIC_RELAXED,
                         __HIP_MEMORY_SCOPE_AGENT);
      __hip_atomic_store(&slots[p * FNB + b], k0, __ATOMIC_RELEASE,
                         __HIP_MEMORY_SCOPE_AGENT);
    }
    if (wid == 0) {
      unsigned long long v = 0ULL;
      if (lane < FNB) {
        do {
          v = __hip_atomic_load(&slots[p * FNB + lane], __ATOMIC_ACQUIRE,
                                __HIP_MEMORY_SCOPE_AGENT);
        } while (v == 0ULL);
      }
#pragma unroll
      for (int off = 32; off > 0; off >>= 1) {
        unsigned long long o = __shfl_down(v, off);
        v = (o > v) ? o : v;
      }
      if (lane == 0) swin = v;
    }
    __syncthreads();
    unsigned long long wkey = swin;
    cur = 0x7fffffff - (int)(wkey & 0xffffffffu);
    float4 cc = xyzs4[cur];
    cx = cc.x; cy = cc.y; cz = cc.z;
    __syncthreads();
  }
}

// gather proto xyz (+norm) and mean node
__global__ void k_gather1(const float* __restrict__ xyz, const int* __restrict__ cent,
                          float4* __restrict__ pxyzs4, float* __restrict__ meann) {
  __shared__ float sx[512], sy[512], sz[512];
  int m = threadIdx.x;
  int c = cent[m];
  float x = xyz[3*c+0], y = xyz[3*c+1], z = xyz[3*c+2];
  pxyzs4[m] = make_float4(x, y, z, x*x + y*y + z*z);
  sx[m] = x; sy[m] = y; sz[m] = z;
  __syncthreads();
  for (int off = 256; off > 0; off >>= 1) {
    if (m < off) { sx[m] += sx[m+off]; sy[m] += sy[m+off]; sz[m] += sz[m+off]; }
    __syncthreads();
  }
  if (m == 0) {
    meann[0] = sx[0] * (1.0f/512.0f);
    meann[1] = sy[0] * (1.0f/512.0f);
    meann[2] = sz[0] * (1.0f/512.0f);
  }
}

// gather proto features
__global__ void k_gatherf(const float* __restrict__ feats, const int* __restrict__ cent,
                          float* __restrict__ pf) {
  int m = blockIdx.x, c = threadIdx.x;
  pf[m*128 + c] = feats[(size_t)cent[m]*128 + c];
}

// ball query (first 10 smallest indices within radius) + PCA curvature -> dist_ge
__global__ void k_ballpca(const float4* __restrict__ xyzs4,
                          const float4* __restrict__ pxyzs4,
                          const float* __restrict__ meann,
                          float* __restrict__ ge) {
  const int m = blockIdx.x, t = threadIdx.x;
  __shared__ int lidx[256][NBALL];
  __shared__ int s_sel[NBALL];
  __shared__ int s_win;
  __shared__ int s_w4[4];
  float4 q = pxyzs4[m];
  int cnt = 0;
  for (int k = 0; k < 256; ++k) {
    int i = (k << 8) + t;
    float4 p = xyzs4[i];
    float dot = q.x*p.x + q.y*p.y + q.z*p.z;
    float d2 = (q.w + p.w) - 2.0f*dot;
    float d = sqrtf(fmaxf(d2, 0.0f));
    if (!(d > 0.04f) && cnt < NBALL) { lidx[t][cnt] = i; cnt++; }
  }
  __syncthreads();
  int hp = 0;
  for (int r = 0; r < NBALL; ++r) {
    int v = (hp < cnt) ? lidx[t][hp] : 0x7fffffff;
#pragma unroll
    for (int off = 32; off > 0; off >>= 1) v = min(v, __shfl_down(v, off));
    if ((t & 63) == 0) s_w4[t >> 6] = v;
    __syncthreads();
    if (t == 0) s_win = min(min(s_w4[0], s_w4[1]), min(s_w4[2], s_w4[3]));
    __syncthreads();
    int w = s_win;
    if (w != 0x7fffffff && hp < cnt && lidx[t][hp] == w) hp++;
    if (t == 0) s_sel[r] = w;
    __syncthreads();
  }
  if (t == 0) {
    float mx = meann[0], my = meann[1], mz = meann[2];
    int first = (s_sel[0] != 0x7fffffff) ? s_sel[0] : NP;
    float c00=0,c01=0,c02=0,c11=0,c12=0,c22=0;
    for (int r = 0; r < NBALL; ++r) {
      int id = s_sel[r];
      if (id == 0x7fffffff) id = first;
      float nx, ny, nz;
      if (id >= NP) { nx = mx; ny = my; nz = mz; }
      else { float4 p = xyzs4[id]; nx = p.x; ny = p.y; nz = p.z; }
      float dx = nx - q.x, dy = ny - q.y, dz = nz - q.z;
      c00 += dx*dx; c01 += dx*dy; c02 += dx*dz;
      c11 += dy*dy; c12 += dy*dz; c22 += dz*dz;
    }
    double e[3];
    eig3((double)(c00/10.0f + 1e-8f), (double)(c01/10.0f + 1e-8f),
         (double)(c02/10.0f + 1e-8f), (double)(c11/10.0f + 1e-8f),
         (double)(c12/10.0f + 1e-8f), (double)(c22/10.0f + 1e-8f), e);
    float l0 = (float)e[0], l1 = (float)e[1], l2r = (float)e[2];
    float l2 = fmaxf(l2r, 1e-8f);
    float f0 = (l2 - l1) / l2, f1 = (l1 - l0) / l2, f2 = l0 / l2;
    ge[m] = sqrtf(f0*f0 + f1*f1 + f2*f2) / sqrtf(3.0f);
  }
}

// E1 = fp16(exp(dist(i,j) * SCNT)); 512 blocks x 256 thr; 2 thr/row, 256 cols each
__global__ void k_e1(const float4* __restrict__ xyzs4,
                     const float4* __restrict__ pxyzs4,
                     unsigned short* __restrict__ E1) {
  const int t = threadIdx.x, b = blockIdx.x;
  __shared__ float4 spp[MP];
  spp[t] = pxyzs4[t];
  spp[t + 256] = pxyzs4[t + 256];
  __syncthreads();
  const int row = b * 128 + (t >> 1);
  const int h = t & 1;
  const float4 q = xyzs4[row];
  us8* dst = (us8*)(E1 + (size_t)row * MP + h * 256);
  for (int g = 0; g < 32; ++g) {
    us8 v;
#pragma unroll
    for (int e = 0; e < 8; ++e) {
      float4 p = spp[h*256 + g*8 + e];
      float dot = q.x*p.x + q.y*p.y + q.z*p.z;
      float dist = sqrtf(fmaxf((q.w + p.w) - 2.0f*dot, 0.0f));
      v[e] = f2h(__expf(dist * SCNT));
    }
    dst[g] = v;
  }
}

// in-place transform: sim(fp16) -> E2 = fp16(exp(sim*NT - B_row)); ebn = exp(-B)
__global__ void k_e2(unsigned short* __restrict__ sim, float* __restrict__ ebn) {
  const int row = blockIdx.x * blockDim.x + threadIdx.x;
  us8* v8 = (us8*)(sim + (size_t)row * MP);
  float B = -1e30f;
  for (int g = 0; g < 64; ++g) {
    us8 u = v8[g];
#pragma unroll
    for (int e = 0; e < 8; ++e) B = fmaxf(B, h2f(u[e]) * NINV_TAU);
  }
  ebn[row] = __expf(-B);
  for (int g = 0; g < 64; ++g) {
    us8 u = v8[g];
    us8 w;
#pragma unroll
    for (int e = 0; e < 8; ++e) w[e] = f2h(__expf(h2f(u[e]) * NINV_TAU - B));
    v8[g] = w;
  }
}

// fused factorized sinkhorn 1: 128 blocks x 512 thr, 1 barrier/iter.
// row/thread; col/thread over the block's 512-row slab; fp32 atomicAdd colsum.
__global__ __launch_bounds__(512) void k_sk1(const unsigned short* __restrict__ E1,
                                             const float* __restrict__ ge,
                                             float* __restrict__ rr_out,
                                             float* __restrict__ gc_out,
                                             float* __restrict__ colsum,
                                             int* __restrict__ slots) {
  const int t = threadIdx.x, b = blockIdx.x;
  __shared__ float sG[MP];
  __shared__ float sGC[MP];
  __shared__ float sRr[512];
  {
    float g = __expf(ge[t] * NINV_TAU);
    sG[t] = g;
    sGC[t] = g;   // C^0 = 1
  }
  __syncthreads();
  const int row = b * 512 + t;
  const us8* e8 = (const us8*)(E1 + (size_t)row * MP);
  for (int it = 0; it < SKI; ++it) {
    // ---- row: V = 1 + sum_j E1_ij * (G_j C_j) ----
    float V = 1.0f;
    for (int g0 = 0; g0 < 64; g0 += 8) {
      us8 u[8];
#pragma unroll
      for (int g = 0; g < 8; ++g) u[g] = e8[g0 + g];
#pragma unroll
      for (int g = 0; g < 8; ++g)
#pragma unroll
        for (int e = 0; e < 8; ++e)
          V = fmaf(h2f(u[g][e]), sGC[(g0+g)*8 + e], V);
    }
    float Rr = 1.0f / V;
    sRr[t] = Rr;
    __syncthreads();
    // ---- col: S_t = sum over slab rows of E1_(row,t) * Rr_row ----
    float S = 0.0f;
    for (int k0 = 0; k0 < 512; k0 += 8) {
      float v[8];
#pragma unroll
      for (int u2 = 0; u2 < 8; ++u2)
        v[u2] = h2f(E1[(size_t)(b*512 + k0 + u2) * MP + t]);
#pragma unroll
      for (int u2 = 0; u2 < 8; ++u2)
        S = fmaf(v[u2], sRr[k0 + u2], S);
    }
    __hip_atomic_fetch_add(&colsum[it * MP + t], S, __ATOMIC_RELAXED,
                           __HIP_MEMORY_SCOPE_AGENT);
    gbar(slots, it + 1, b, t);
    // ---- new C from summed column ----
    {
      float Sm = rd_f32(&colsum[it * MP + t]);
      float Cj = 1.0f / fmaf(sG[t], Sm, 1.0f);
      sGC[t] = sG[t] * Cj;
    }
    __syncthreads();
  }
  rr_out[row] = sRr[t];
  if (b == 0) gc_out[t] = sGC[t];
}

// partial gamma^T @ feats using E1: gamma = E1 * gc_j * rr_i
__global__ void k_pfeat_part(const unsigned short* __restrict__ E1,
                             const float* __restrict__ gc, const float* __restrict__ rr,
                             const float* __restrict__ feats,
                             float* __restrict__ part) {
  const int t = threadIdx.x;
  const int nc = blockIdx.x;
  const int mt = blockIdx.y;
  __shared__ float sgc[64];
  __shared__ float sf[64][128];
  __shared__ float sw[64][64];
  __shared__ float srr[64];
  if (t < 64) sgc[t] = gc[mt*64 + t];
  const int mg = t >> 4;
  const int cg = t & 15;
  float acc[8][8];
#pragma unroll
  for (int a = 0; a < 8; ++a)
#pragma unroll
    for (int b2 = 0; b2 < 8; ++b2) acc[a][b2] = 0.0f;
  for (int bt = 0; bt < 16; ++bt) {
    int n0 = nc*1024 + bt*64;
    __syncthreads();
    for (int q2 = t; q2 < 2048; q2 += 128) {
      int row = q2 >> 5, c4 = q2 & 31;
      ((float4*)&sf[row][0])[c4] = ((const float4*)feats)[(size_t)(n0+row)*32 + c4];
    }
    if (t < 64) srr[t] = rr[n0 + t];
    __syncthreads();
    for (int q2 = t; q2 < 4096; q2 += 128) {
      int nl = q2 >> 6, ml = q2 & 63;
      float ev = h2f(E1[(size_t)(n0+nl)*MP + mt*64 + ml]);
      sw[nl][ml] = ev * sgc[ml] * srr[nl];
    }
    __syncthreads();
#pragma unroll 8
    for (int n = 0; n < 64; ++n) {
      float4 w0 = ((float4*)&sw[n][0])[mg*2];
      float4 w1 = ((float4*)&sw[n][0])[mg*2+1];
      float4 f0 = ((float4*)&sf[n][0])[cg*2];
      float4 f1 = ((float4*)&sf[n][0])[cg*2+1];
      float wv[8] = {w0.x,w0.y,w0.z,w0.w,w1.x,w1.y,w1.z,w1.w};
      float fv[8] = {f0.x,f0.y,f0.z,f0.w,f1.x,f1.y,f1.z,f1.w};
#pragma unroll
      for (int a = 0; a < 8; ++a)
#pragma unroll
        for (int b2 = 0; b2 < 8; ++b2) acc[a][b2] = fmaf(wv[a], fv[b2], acc[a][b2]);
    }
  }
  for (int a = 0; a < 8; ++a) {
    int m = mt*64 + mg*8 + a;
    float* dst = &part[((size_t)nc*MP + m)*128 + cg*8];
    ((float4*)dst)[0] = make_float4(acc[a][0], acc[a][1], acc[a][2], acc[a][3]);
    ((float4*)dst)[1] = make_float4(acc[a][4], acc[a][5], acc[a][6], acc[a][7]);
  }
}

__global__ void k_pfeat_red(const float* __restrict__ part, const float* __restrict__ pf,
                            float* __restrict__ p1) {
  int idx = blockIdx.x*256 + threadIdx.x;
  float s = 0.0f;
  for (int ncb = 0; ncb < 64; ++ncb) s += part[(size_t)ncb*MP*128 + idx];
  p1[idx] = 0.5f*pf[idx] + 0.5f*s;
}

// sim column + top-20 aggregation -> p2
__global__ void k_simtopk(const float* __restrict__ p1, float* __restrict__ p2) {
  const int m = blockIdx.x, t = threadIdx.x;
  __shared__ float spm[128];
  __shared__ float scol[MP];
  __shared__ float sval[20];
  __shared__ int   sid[20];
  __shared__ float sredv[2];
  __shared__ int   sredi[2];
  __shared__ float sden;
  spm[t] = p1[m*128 + t];
  __syncthreads();
  for (int kk = t; kk < MP; kk += 128) {
    float a = 0.0f;
    const float* row = &p1[kk*128];
#pragma unroll 8
    for (int c2 = 0; c2 < 128; ++c2) a = fmaf(row[c2], spm[c2], a);
    scol[kk] = a * SCF;
  }
  __syncthreads();
  for (int rs = 0; rs < 20; ++rs) {
    float bv = -1e30f; int bI = 1 << 30;
    for (int kk = t; kk < MP; kk += 128) {
      float v = scol[kk];
      if (v > bv) { bv = v; bI = kk; }
    }
#pragma unroll
    for (int off = 32; off > 0; off >>= 1) {
      float ov = __shfl_down(bv, off); int oi = __shfl_down(bI, off);
      if (ov > bv || (ov == bv && oi < bI)) { bv = ov; bI = oi; }
    }
    if ((t & 63) == 0) { sredv[t>>6] = bv; sredi[t>>6] = bI; }
    __syncthreads();
    if (t == 0) {
      float v1 = sredv[1]; int i1 = sredi[1];
      if (v1 > bv || (v1 == bv && i1 < bI)) { bv = v1; bI = i1; }
      sval[rs] = bv; sid[rs] = bI;
      scol[bI] = -1e30f;
    }
    __syncthreads();
  }
  if (t == 0) {
    float s = 0.0f;
    for (int rs = 0; rs < 20; ++rs) s += sval[rs];
    sden = fmaxf(s, 1e-4f);
  }
  __syncthreads();
  float a = 0.0f;
  float den = sden;
  for (int rs = 0; rs < 20; ++rs) {
    float w = sval[rs] / den;
    a = fmaf(w, p1[sid[rs]*128 + t], a);
  }
  p2[m*128 + t] = 0.5f*p1[m*128 + t] + 0.5f*a;
}

// sim_pt = feats @ p2^T * sc (stored fp16) : grid (1024, 8), block 256
__global__ void k_simpt(const float* __restrict__ feats, const float* __restrict__ p2,
                        __half* __restrict__ sim) {
  const int t = threadIdx.x;
  const int nt = blockIdx.x;
  const int mt = blockIdx.y;
  __shared__ float sa[64][68];
  __shared__ float sb[64][68];
  const int tn = t >> 4, tm = t & 15;
  float acc[4][4];
#pragma unroll
  for (int x = 0; x < 4; ++x)
#pragma unroll
    for (int y = 0; y < 4; ++y) acc[x][y] = 0.0f;
  for (int kh = 0; kh < 2; ++kh) {
    __syncthreads();
    for (int q2 = t; q2 < 1024; q2 += 256) {
      int row = q2 >> 4, c4 = q2 & 15;
      ((float4*)&sa[row][0])[c4] =
          ((const float4*)feats)[(size_t)(nt*64+row)*32 + kh*16 + c4];
      ((float4*)&sb[row][0])[c4] =
          ((const float4*)p2)[(size_t)(mt*64+row)*32 + kh*16 + c4];
    }
    __syncthreads();
    for (int k = 0; k < 64; ++k) {
      float av[4], bv[4];
#pragma unroll
      for (int x = 0; x < 4; ++x) av[x] = sa[tn*4+x][k];
#pragma unroll
      for (int y = 0; y < 4; ++y) bv[y] = sb[tm*4+y][k];
#pragma unroll
      for (int x = 0; x < 4; ++x)
#pragma unroll
        for (int y = 0; y < 4; ++y) acc[x][y] = fmaf(av[x], bv[y], acc[x][y]);
    }
  }
  for (int x = 0; x < 4; ++x)
    for (int y = 0; y < 4; ++y) {
      int n = nt*64 + tn*4 + x, mc = mt*64 + tm*4 + y;
      sim[(size_t)n*MP + mc] = __float2half(acc[x][y] * SCF);
    }
}

// fused factorized sinkhorn 2 over E2: 128 blocks x 512 thr, 1 barrier/iter.
__global__ __launch_bounds__(512) void k_sk2(const unsigned short* __restrict__ E2,
                                             const float* __restrict__ ebn,
                                             float* __restrict__ rr_out,
                                             float* __restrict__ c_out,
                                             float* __restrict__ colsum,
                                             int* __restrict__ slots) {
  const int t = threadIdx.x, b = blockIdx.x;
  __shared__ float sC[MP];
  __shared__ float sRr[512];
  sC[t] = 1.0f;
  __syncthreads();
  const int row = b * 512 + t;
  const us8* e8 = (const us8*)(E2 + (size_t)row * MP);
  const float eb = ebn[row];
  for (int it = 0; it < SKI; ++it) {
    float V = eb;
    for (int g0 = 0; g0 < 64; g0 += 8) {
      us8 u[8];
#pragma unroll
      for (int g = 0; g < 8; ++g) u[g] = e8[g0 + g];
#pragma unroll
      for (int g = 0; g < 8; ++g)
#pragma unroll
        for (int e = 0; e < 8; ++e)
          V = fmaf(h2f(u[g][e]), sC[(g0+g)*8 + e], V);
    }
    float R = 1.0f / V;
    sRr[t] = R;
    __syncthreads();
    float S = 0.0f;
    for (int k0 = 0; k0 < 512; k0 += 8) {
      float v[8];
#pragma unroll
      for (int u2 = 0; u2 < 8; ++u2)
        v[u2] = h2f(E2[(size_t)(b*512 + k0 + u2) * MP + t]);
#pragma unroll
      for (int u2 = 0; u2 < 8; ++u2)
        S = fmaf(v[u2], sRr[k0 + u2], S);
    }
    __hip_atomic_fetch_add(&colsum[it * MP + t], S, __ATOMIC_RELAXED,
                           __HIP_MEMORY_SCOPE_AGENT);
    gbar(slots, it + 1, b, t);
    {
      float Sm = rd_f32(&colsum[it * MP + t]);
      sC[t] = 1.0f / (Sm + 1.0f);
    }
    __syncthreads();
  }
  rr_out[row] = sRr[t];
  if (b == 0) c_out[t] = sC[t];
}

// refined = 0.5*feats + 0.5 * w @ p2, w = E2 * R_i * C_j
__global__ void k_refined(const unsigned short* __restrict__ E2,
                          const float* __restrict__ rr, const float* __restrict__ cc,
                          const float* __restrict__ p2,
                          const float* __restrict__ feats, float* __restrict__ out) {
  const int t = threadIdx.x;
  const int nb = blockIdx.x;  // 64 rows per block
  __shared__ float sp[64][128];
  __shared__ float sw[64][68];
  __shared__ float srr[64], scc[64];
  const int tn = t >> 5, tc = t & 31;
  if (t < 64) srr[t] = rr[nb*64 + t];
  float acc[8][4];
#pragma unroll
  for (int a = 0; a < 8; ++a)
#pragma unroll
    for (int b2 = 0; b2 < 4; ++b2) acc[a][b2] = 0.0f;
  for (int mt2 = 0; mt2 < 8; ++mt2) {
    __syncthreads();
    for (int q2 = t; q2 < 2048; q2 += 256) {
      int row = q2 >> 5, c4 = q2 & 31;
      ((float4*)&sp[row][0])[c4] = ((const float4*)p2)[(size_t)(mt2*64+row)*32 + c4];
    }
    if (t < 64) scc[t] = cc[mt2*64 + t];
    __syncthreads();
    for (int q2 = t; q2 < 4096; q2 += 256) {
      int nl = q2 >> 6, ml = q2 & 63;
      float ev = h2f(E2[(size_t)(nb*64+nl)*MP + mt2*64 + ml]);
      sw[nl][ml] = ev * srr[nl] * scc[ml];
    }
    __syncthreads();
    for (int mm2 = 0; mm2 < 64; ++mm2) {
      float4 pv = ((float4*)&sp[mm2][0])[tc];
      float wv[8];
#pragma unroll
      for (int a = 0; a < 8; ++a) wv[a] = sw[tn*8+a][mm2];
#pragma unroll
      for (int a = 0; a < 8; ++a) {
        acc[a][0] = fmaf(wv[a], pv.x, acc[a][0]);
        acc[a][1] = fmaf(wv[a], pv.y, acc[a][1]);
        acc[a][2] = fmaf(wv[a], pv.z, acc[a][2]);
        acc[a][3] = fmaf(wv[a], pv.w, acc[a][3]);
      }
    }
  }
  for (int a = 0; a < 8; ++a) {
    int row = nb*64 + tn*8 + a;
    float4 f = ((const float4*)feats)[(size_t)row*32 + tc];
    float4 o;
    o.x = 0.5f*f.x + 0.5f*acc[a][0];
    o.y = 0.5f*f.y + 0.5f*acc[a][1];
    o.z = 0.5f*f.z + 0.5f*acc[a][2];
    o.w = 0.5f*f.w + 0.5f*acc[a][3];
    ((float4*)out)[(size_t)row*32 + tc] = o;
  }
}

// ---------------- launcher ----------------

extern "C" void kernel_launch(void* const* d_in, const int* in_sizes, int n_in,
                              void* d_out, int out_size, void* d_ws, size_t ws_size,
                              hipStream_t stream) {
  (void)in_sizes; (void)n_in; (void)out_size; (void)ws_size;
  const float* xyz   = (const float*)d_in[0];
  const float* feats = (const float*)d_in[1];
  float* out = (float*)d_out;
  char* ws = (char*)d_ws;

  auto al = [](size_t x) { return (x + 255) & ~(size_t)255; };
  // E-buffer (fp16, 64MB): holds E1 (sk1/pfeat), later overwritten by sim -> E2
  unsigned short* Ebuf = (unsigned short*)ws;
  size_t o = al((size_t)NP * MP * 2);
  float4* xyzs4 = (float4*)(ws + o); o += al((size_t)NP * 16);
  float* rbuf   = (float*)(ws + o);  o += al((size_t)NP * 4);
  float* ebnbuf = (float*)(ws + o);  o += al((size_t)NP * 4);
  float* cbuf   = (float*)(ws + o);  o += al((size_t)MP * 4);
  float* gcbuf  = (float*)(ws + o);  o += al((size_t)MP * 4);
  int*   cent   = (int*)(ws + o);    o += al((size_t)MP * 4);
  float4* pxyzs4 = (float4*)(ws + o); o += al((size_t)MP * 16);
  float* ge     = (float*)(ws + o);  o += al((size_t)MP * 4);
  float* meann  = (float*)(ws + o);  o += al((size_t)256);
  float* pf     = (float*)(ws + o);  o += al((size_t)MP * 128 * 4);
  float* p1     = (float*)(ws + o);  o += al((size_t)MP * 128 * 4);
  float* p2     = (float*)(ws + o);  o += al((size_t)MP * 128 * 4);
  float* colsumA = (float*)(ws + o); o += al((size_t)SKI * MP * 4);
  float* colsumB = (float*)(ws + o); o += al((size_t)SKI * MP * 4);
  unsigned long long* fslots = (unsigned long long*)(ws + o);
  o += al((size_t)3 * FNB * 8);
  int* bar1 = (int*)(ws + o); o += al((size_t)SKB2 * 4);
  int* bar2 = (int*)(ws + o); o += al((size_t)SKB2 * 4);
  float* partA = (float*)(ws + o); o += al((size_t)64 * MP * 128 * 4);

  hipMemsetAsync(colsumA, 0, (size_t)2 * SKI * MP * 4 + 256, stream);
  k_prep<<<dim3(256), dim3(256), 0, stream>>>(xyz, xyzs4, fslots, bar1, bar2);
  k_fps3<<<dim3(FNB), dim3(FPT), 0, stream>>>(xyzs4, cent, fslots);
  k_gather1<<<dim3(1), dim3(512), 0, stream>>>(xyz, cent, pxyzs4, meann);
  k_gatherf<<<dim3(512), dim3(128), 0, stream>>>(feats, cent, pf);
  k_ballpca<<<dim3(512), dim3(256), 0, stream>>>(xyzs4, pxyzs4, meann, ge);

  // sinkhorn 1 on precomputed E1 (factorized, exp-free, fence-free)
  k_e1<<<dim3(512), dim3(256), 0, stream>>>(xyzs4, pxyzs4, Ebuf);
  k_sk1<<<dim3(SKB2), dim3(512), 0, stream>>>(Ebuf, ge, rbuf, gcbuf, colsumA, bar1);

  k_pfeat_part<<<dim3(64, 8), dim3(128), 0, stream>>>(Ebuf, gcbuf, rbuf, feats, partA);
  k_pfeat_red<<<dim3(256), dim3(256), 0, stream>>>(partA, pf, p1);
  k_simtopk<<<dim3(512), dim3(128), 0, stream>>>(p1, p2);

  // sim -> E2 (in place) -> sinkhorn 2 -> refined
  k_simpt<<<dim3(1024, 8), dim3(256), 0, stream>>>(feats, p2, (__half*)Ebuf);
  k_e2<<<dim3(256), dim3(256), 0, stream>>>(Ebuf, ebnbuf);
  k_sk2<<<dim3(SKB2), dim3(512), 0, stream>>>(Ebuf, ebnbuf, rbuf, cbuf, colsumB, bar2);
  k_refined<<<dim3(1024), dim3(256), 0, stream>>>(Ebuf, rbuf, cbuf, p2, feats, out);
}